// Round 2
// baseline (323.888 us; speedup 1.0000x reference)
//
#include <hip/hip_runtime.h>
#include <math.h>

#define T_DIM 8192
#define IN_DIM 1024
#define TRACE 64
#define CTX 16
#define OUT_DIM 1024
#define KMIX 2048

typedef __attribute__((ext_vector_type(8))) short bf16x8;
typedef __attribute__((ext_vector_type(4))) float f32x4;
typedef __attribute__((ext_vector_type(16))) float f32x16;

__device__ __forceinline__ unsigned short f2bf(float f) {
    unsigned int u = __float_as_uint(f);
    u = (u + 0x7FFFu + ((u >> 16) & 1u)) >> 16;
    return (unsigned short)u;
}
__device__ __forceinline__ float bf2f(unsigned short b) {
    return __uint_as_float(((unsigned int)b) << 16);
}

__device__ __forceinline__ void gl2lds16(const void* g, void* l) {
    __builtin_amdgcn_global_load_lds(
        (const __attribute__((address_space(1))) unsigned int*)g,
        (__attribute__((address_space(3))) unsigned int*)l,
        16, 0, 0);
}

// ---------------- ws layout (float offsets) ----------------
// gxT   fp32 [64][8192]      @ 0         (524288 f)
// zinTb bf16 [2048][8192]    @ 524288    (8388608 f)
// zinb  bf16 [8192][2048]    @ 8912896   (8388608 f)
// xb    bf16 [8192][1024]    @ 17301504  (4194304 f)
// gob   bf16 [1024][1024]    @ 21495808  (524288 f)
// skb   bf16 [1024][1024]    @ 22020096  (524288 f)
// mixb  bf16 [1024][2048]    @ 22544384  (1048576 f)
// zg    bf16 [8192][1024]    @ 23592960  (4194304 f)   [pwb/gwb borrow pre-gA]
// sk2   bf16 [8192][1024]    @ 27787264  (4194304 f)
// fstate fp32 [2048]         @ 31981568
// mask  u8   [8192]          @ 31983616

// ---------------- C0: fp32 -> bf16 conversions + start-mask normalization (block 0) -----------
__global__ __launch_bounds__(256) void c0_conv(const float* __restrict__ x,
        const float* __restrict__ gw, const float* __restrict__ sw, const float* __restrict__ mw,
        const float* __restrict__ pw, const float* __restrict__ giw,
        const void* __restrict__ startp,
        unsigned short* __restrict__ xb, unsigned short* __restrict__ gob,
        unsigned short* __restrict__ skb, unsigned short* __restrict__ mixb,
        unsigned short* __restrict__ pwb, unsigned short* __restrict__ gwb,
        unsigned char* __restrict__ mask)
{
    if (blockIdx.x == 0) {
        __shared__ int nonbool;
        int tid = threadIdx.x;
        if (tid == 0) nonbool = 0;
        __syncthreads();
        const unsigned int* wv = (const unsigned int*)startp;
        #pragma unroll
        for (int p = 0; p < 8; p++) {
            unsigned int a = wv[tid * 8 + p];
            if (a > 1u) nonbool = 1;
        }
        __syncthreads();
        if (nonbool) {
            const unsigned char* s8 = (const unsigned char*)startp;
            for (int i = tid; i < T_DIM; i += 256) mask[i] = (unsigned char)(s8[i] != 0);
        } else {
            const int* s32 = (const int*)startp;
            for (int i = tid; i < T_DIM; i += 256) mask[i] = (unsigned char)(s32[i] != 0);
        }
    }
    const size_t QX = 2097152, QG = 262144, QS = 262144, QM = 524288, QP = 16384, QI = 16384;
    const size_t total = QX + QG + QS + QM + QP + QI;
    for (size_t q = (size_t)blockIdx.x * blockDim.x + threadIdx.x; q < total;
         q += (size_t)gridDim.x * blockDim.x) {
        const float* src; unsigned short* dst; size_t i;
        if (q < QX)                  { src = x;   dst = xb;   i = q; }
        else if (q < QX+QG)          { src = gw;  dst = gob;  i = q - QX; }
        else if (q < QX+QG+QS)       { src = sw;  dst = skb;  i = q - QX - QG; }
        else if (q < QX+QG+QS+QM)    { src = mw;  dst = mixb; i = q - QX - QG - QS; }
        else if (q < QX+QG+QS+QM+QP) { src = pw;  dst = pwb;  i = q - QX - QG - QS - QM; }
        else                         { src = giw; dst = gwb;  i = q - QX - QG - QS - QM - QP; }
        float4 v = *(const float4*)(src + i * 4);
        ushort4 o;
        o.x = f2bf(v.x); o.y = f2bf(v.y); o.z = f2bf(v.z); o.w = f2bf(v.w);
        *(ushort4*)(dst + i * 4) = o;
    }
}

// ---------------- K1: MFMA gated_x, 256 blocks of 32t x 128m, swizzled LDS --------------------
__global__ __launch_bounds__(256) void k1_mfma(const unsigned short* __restrict__ xb,
        const unsigned short* __restrict__ pwb, const unsigned short* __restrict__ gwb,
        const float* __restrict__ pre_b, const float* __restrict__ gi_b,
        float* __restrict__ gxT)
{
    __shared__ __align__(16) unsigned short As[1024];
    __shared__ __align__(16) unsigned short Bs[4096];
    __shared__ float sgE[64][33];

    const int tid = threadIdx.x;
    const int t0 = blockIdx.x * 32;
    const int lane = tid & 63, w = tid >> 6;
    const int quad = lane >> 4, l16 = lane & 15;
    const int r = tid >> 2, s4 = tid & 3;
    const int csw = (s4 - ((r >> 1) & 3)) & 3;

    f32x4 acc[2][2];
    const f32x4 zero4 = {0.f, 0.f, 0.f, 0.f};
    #pragma unroll
    for (int mi = 0; mi < 2; mi++)
        #pragma unroll
        for (int ni = 0; ni < 2; ni++) acc[mi][ni] = zero4;

    const int sfr = (quad + ((l16 >> 1) & 3)) & 3;

    for (int k0 = 0; k0 < IN_DIM; k0 += 32) {
        __syncthreads();
        if (tid < 128) {
            int ra = tid >> 2;
            int ca = ((tid & 3) - ((ra >> 1) & 3)) & 3;
            gl2lds16(xb + (size_t)(t0 + ra) * IN_DIM + k0 + ca * 8, As + tid * 8);
        }
        gl2lds16(pwb + (size_t)r * IN_DIM + k0 + csw * 8, Bs + tid * 8);
        gl2lds16(gwb + (size_t)r * IN_DIM + k0 + csw * 8, Bs + 2048 + tid * 8);
        asm volatile("s_waitcnt vmcnt(0)" ::: "memory");
        __syncthreads();
        bf16x8 af[2], bf[2];
        #pragma unroll
        for (int mi = 0; mi < 2; mi++)
            af[mi] = *(const bf16x8*)&As[(mi * 16 + l16) * 32 + sfr * 8];
        #pragma unroll
        for (int ni = 0; ni < 2; ni++)
            bf[ni] = *(const bf16x8*)&Bs[(w * 32 + ni * 16 + l16) * 32 + sfr * 8];
        #pragma unroll
        for (int mi = 0; mi < 2; mi++)
            #pragma unroll
            for (int ni = 0; ni < 2; ni++)
                acc[mi][ni] = __builtin_amdgcn_mfma_f32_16x16x32_bf16(af[mi], bf[ni], acc[mi][ni], 0, 0, 0);
    }

    if (w >= 2) {
        #pragma unroll
        for (int mi = 0; mi < 2; mi++)
            #pragma unroll
            for (int ni = 0; ni < 2; ni++) {
                int mg = (w - 2) * 32 + ni * 16 + l16;
                float gb = gi_b[mg];
                #pragma unroll
                for (int rr = 0; rr < 4; rr++) {
                    int tl = mi * 16 + quad * 4 + rr;
                    sgE[mg][tl] = 1.f / (1.f + expf(-(acc[mi][ni][rr] + gb)));
                }
            }
    }
    __syncthreads();
    if (w < 2) {
        #pragma unroll
        for (int mi = 0; mi < 2; mi++)
            #pragma unroll
            for (int ni = 0; ni < 2; ni++) {
                int mp = w * 32 + ni * 16 + l16;
                float pb = pre_b[mp];
                float4 o;
                float* po = &o.x;
                #pragma unroll
                for (int rr = 0; rr < 4; rr++) {
                    int tl = mi * 16 + quad * 4 + rr;
                    po[rr] = (acc[mi][ni][rr] + pb) * sgE[mp][tl];
                }
                *(float4*)&gxT[(size_t)mp * T_DIM + t0 + mi * 16 + quad * 4] = o;
            }
    }
}

// ---------------- K2: resettable complex scan; LDS-staged coalesced output --------------------
__global__ __launch_bounds__(128) void k2_scan(const float* __restrict__ gxT,
        const unsigned char* __restrict__ mask8,
        const float* __restrict__ state_re, const float* __restrict__ state_im,
        const float* __restrict__ ffa_a, const float* __restrict__ ffa_b,
        unsigned short* __restrict__ zinTb, float* __restrict__ fstate)
{
    const int m = blockIdx.x >> 4;
    const int c = blockIdx.x & 15;
    const int j = threadIdx.x;
    __shared__ float Br[128], Bi[128], Er[128], Ei[128];
    __shared__ unsigned char Rf[128];
    __shared__ unsigned int SB[128 * 33];

    const float am = -fabsf(ffa_a[m]);
    const float bc = ffa_b[c];
    const float er = expf(am);
    const float gr = er * cosf(bc);
    const float gi = er * sinf(bc);

    const float* gx = gxT + (size_t)m * T_DIM;
    const int t0 = j * 64;

    unsigned long long rmask = 0ull;
    float sre = 0.f, sim = 0.f;
    bool r = false;
    #pragma unroll 8
    for (int i = 0; i < 64; i++) {
        int t = t0 + i;
        if (mask8[t]) { rmask |= 1ull << i; sre = 0.f; sim = 0.f; r = true; }
        else { float tr_ = sre * gr - sim * gi; sim = sre * gi + sim * gr; sre = tr_; }
        sre += gx[t];
    }
    Br[j] = sre; Bi[j] = sim; Rf[j] = r ? 1 : 0;
    __syncthreads();
    if (j == 0) {
        float e64  = expf(64.f * am);
        float g64r = e64 * cosf(64.f * bc);
        float g64i = e64 * sinf(64.f * bc);
        float pr = state_re[m * CTX + c], pi = state_im[m * CTX + c];
        for (int q = 0; q < 128; q++) {
            Er[q] = pr; Ei[q] = pi;
            if (Rf[q]) { pr = Br[q]; pi = Bi[q]; }
            else {
                float nr = pr * g64r - pi * g64i + Br[q];
                pi       = pr * g64i + pi * g64r + Bi[q];
                pr = nr;
            }
        }
    }
    __syncthreads();
    sre = Er[j]; sim = Ei[j];
    unsigned int ore[32], oim[32];
    #pragma unroll
    for (int i = 0; i < 64; i++) {
        int t = t0 + i;
        if (rmask & (1ull << i)) { sre = 0.f; sim = 0.f; }
        else { float tr_ = sre * gr - sim * gi; sim = sre * gi + sim * gr; sre = tr_; }
        sre += gx[t];
        unsigned short hr = f2bf(sre), hi_ = f2bf(sim);
        if (i & 1) { ore[i >> 1] |= ((unsigned int)hr) << 16; oim[i >> 1] |= ((unsigned int)hi_) << 16; }
        else       { ore[i >> 1]  = hr;                        oim[i >> 1]  = hi_; }
    }
    if (j == 127) {
        int p = m * CTX + c;
        fstate[p]        = sre;
        fstate[1024 + p] = sim;
    }

    unsigned short* zreb = zinTb + (size_t)(m * 32 + c)      * T_DIM;
    unsigned short* zimb = zinTb + (size_t)(m * 32 + 16 + c) * T_DIM;

    #pragma unroll
    for (int q = 0; q < 32; q++) SB[j * 33 + q] = ore[q];
    __syncthreads();
    #pragma unroll
    for (int it = 0; it < 8; it++) {
        int g = (it * 128 + j) * 4;
        int jj = g >> 5, qq = g & 31;
        uint4 v = *(uint4*)&SB[jj * 33 + qq];
        *(uint4*)(zreb + g * 2) = v;
    }
    __syncthreads();
    #pragma unroll
    for (int q = 0; q < 32; q++) SB[j * 33 + q] = oim[q];
    __syncthreads();
    #pragma unroll
    for (int it = 0; it < 8; it++) {
        int g = (it * 128 + j) * 4;
        int jj = g >> 5, qq = g & 31;
        uint4 v = *(uint4*)&SB[jj * 33 + qq];
        *(uint4*)(zimb + g * 2) = v;
    }
}

// ---------------- T3: transpose zinTb[k][t] -> zinb[t][k], 64x64 tiles -------------------------
__global__ __launch_bounds__(256) void t3_tr(const unsigned short* __restrict__ zinTb,
                                             unsigned short* __restrict__ zinb)
{
    __shared__ unsigned short S[64][72];
    const int k0 = blockIdx.x * 64, t0 = blockIdx.y * 64;
    const int tid = threadIdx.x;
    {
        int kr = tid >> 3, tc = (tid & 7) * 8;
        #pragma unroll
        for (int p = 0; p < 2; p++) {
            int k = kr + p * 32;
            ushort4 a = *(const ushort4*)&zinTb[(size_t)(k0 + k) * T_DIM + t0 + tc];
            ushort4 b = *(const ushort4*)&zinTb[(size_t)(k0 + k) * T_DIM + t0 + tc + 4];
            *(ushort4*)&S[k][tc]     = a;
            *(ushort4*)&S[k][tc + 4] = b;
        }
    }
    __syncthreads();
    {
        int tr = tid >> 3, kc = (tid & 7) * 8;
        #pragma unroll
        for (int p = 0; p < 2; p++) {
            int t = tr + p * 32;
            ushort4 o1, o2;
            o1.x = S[kc+0][t]; o1.y = S[kc+1][t]; o1.z = S[kc+2][t]; o1.w = S[kc+3][t];
            o2.x = S[kc+4][t]; o2.y = S[kc+5][t]; o2.z = S[kc+6][t]; o2.w = S[kc+7][t];
            *(ushort4*)&zinb[(size_t)(t0 + t) * KMIX + k0 + kc]     = o1;
            *(ushort4*)&zinb[(size_t)(t0 + t) * KMIX + k0 + kc + 4] = o2;
        }
    }
}

// ---------------- GA: 128x64 tile, 4 waves, BK=32, double-buffered, 4 blocks/CU ---------------
// Round-2 theory: r1's counted-vmcnt depth-2 on 1 block/CU was neutral -> constraint is
// occupancy (2 waves/SIMD, lockstep barriers). This version trades LDS-read ratio for TLP:
// 1024 blocks x 256 thr, 32KB LDS -> 4 blocks/CU = 16 waves/CU. Independent blocks are never
// barrier-synced, so one block's LDS-read burst overlaps another's MFMA cluster naturally.
// STAGE issued at top of iter (early-issue); mix prefetch issued before fused epilogue (T14).
__global__ __launch_bounds__(256, 4) void gA_gemm(
        const unsigned short* __restrict__ xb,   const unsigned short* __restrict__ zinb,
        const unsigned short* __restrict__ gob,  const unsigned short* __restrict__ skb,
        const unsigned short* __restrict__ mixb,
        const float* __restrict__ go_b, const float* __restrict__ skip_b, const float* __restrict__ mix_b,
        unsigned short* __restrict__ zg, unsigned short* __restrict__ sk2)
{
    __shared__ __align__(16) unsigned short L[16384];   // 2 buffers x (A[128][32] | B[64][32] | C[64][32])
    const int tid = threadIdx.x;
    const int b = blockIdx.x;
    const int xcd = b & 7, q = b >> 3;                  // q in [0,128)
    const int t0 = (xcd * 8 + (q >> 4)) * 128;          // 64 t-tiles of 128 (XCD-contiguous)
    const int n0 = (q & 15) * 64;                       // 16 n-tiles of 64

    const int lane = tid & 63, w = tid >> 6;            // 4 waves
    const int wm = w >> 1, wn = w & 1;                  // 2x2 wave grid, wave tile 64x32
    const int l31 = lane & 31, h = lane >> 5;
    const int r = tid >> 2;                             // [0,64)
    const int csw = ((tid & 3) - ((r >> 1) & 3)) & 3;   // staging chunk permutation
    const int c8 = csw * 8;
    const int srot = (l31 >> 1) & 3;                    // fragment de-swizzle rotation
    const int dst8 = tid * 8;

    f32x16 accg[2], acck[2];
    #pragma unroll
    for (int mi = 0; mi < 2; mi++)
        #pragma unroll
        for (int e = 0; e < 16; e++) { accg[mi][e] = 0.f; acck[mi][e] = 0.f; }

    // ---- fused phase: go + skip (shared A = xb), K = 1024, 32 tiles of BK=32 ----
    {
        const unsigned short* gA0 = xb  + (size_t)(t0 + r)      * IN_DIM + c8;
        const unsigned short* gA1 = xb  + (size_t)(t0 + 64 + r) * IN_DIM + c8;
        const unsigned short* gB0 = gob + (size_t)(n0 + r)      * IN_DIM + c8;
        const unsigned short* gC0 = skb + (size_t)(n0 + r)      * IN_DIM + c8;

#define STAGE_F(bufi, kof) do {                         \
        unsigned short* _b = &L[(bufi) * 8192];         \
        gl2lds16(gA0 + (kof), _b + dst8);               \
        gl2lds16(gA1 + (kof), _b + 2048 + dst8);        \
        gl2lds16(gB0 + (kof), _b + 4096 + dst8);        \
        gl2lds16(gC0 + (kof), _b + 6144 + dst8);        \
    } while (0)

        STAGE_F(0, 0);
        asm volatile("s_waitcnt vmcnt(0)" ::: "memory");
        __builtin_amdgcn_s_barrier();

        for (int t = 0; t < 32; ++t) {
            if (t + 1 < 32) STAGE_F((t + 1) & 1, (t + 1) * 32);
            const unsigned short* As = &L[(t & 1) * 8192];
            const unsigned short* Bs = As + 4096;
            const unsigned short* Cs = As + 6144;
            #pragma unroll
            for (int kh = 0; kh < 2; kh++) {
                const int so = ((kh * 2 + h + srot) & 3) * 8;
                bf16x8 af0 = *(const bf16x8*)&As[(wm * 64 + l31) * 32 + so];
                bf16x8 af1 = *(const bf16x8*)&As[(wm * 64 + 32 + l31) * 32 + so];
                bf16x8 bg  = *(const bf16x8*)&Bs[(wn * 32 + l31) * 32 + so];
                bf16x8 bk  = *(const bf16x8*)&Cs[(wn * 32 + l31) * 32 + so];
                __builtin_amdgcn_s_setprio(1);
                accg[0] = __builtin_amdgcn_mfma_f32_32x32x16_bf16(af0, bg, accg[0], 0, 0, 0);
                acck[0] = __builtin_amdgcn_mfma_f32_32x32x16_bf16(af0, bk, acck[0], 0, 0, 0);
                accg[1] = __builtin_amdgcn_mfma_f32_32x32x16_bf16(af1, bg, accg[1], 0, 0, 0);
                acck[1] = __builtin_amdgcn_mfma_f32_32x32x16_bf16(af1, bk, acck[1], 0, 0, 0);
                __builtin_amdgcn_s_setprio(0);
            }
            asm volatile("s_waitcnt vmcnt(0)" ::: "memory");
            __builtin_amdgcn_s_barrier();
        }
#undef STAGE_F
    }

    // ---- issue first mix-phase stage EARLY so HBM latency hides under the sigmoid epilogue ----
    const unsigned short* mA0 = zinb + (size_t)(t0 + r)      * KMIX + c8;
    const unsigned short* mA1 = zinb + (size_t)(t0 + 64 + r) * KMIX + c8;
    const unsigned short* mB0 = mixb + (size_t)(n0 + r)      * KMIX + c8;

#define STAGE_M(bufi, kof) do {                         \
        unsigned short* _b = &L[(bufi) * 8192];         \
        gl2lds16(mA0 + (kof), _b + dst8);               \
        gl2lds16(mA1 + (kof), _b + 2048 + dst8);        \
        gl2lds16(mB0 + (kof), _b + 4096 + dst8);        \
    } while (0)

    STAGE_M(0, 0);

    // sigmoid (packed bf16 pairs) + sk2 write
    unsigned int sigp[16];
    {
        const int n = n0 + wn * 32 + l31;
        const float gb = go_b[n];
        const float sb_ = skip_b[n];
        #pragma unroll
        for (int mi = 0; mi < 2; mi++) {
            #pragma unroll
            for (int reg = 0; reg < 16; reg++) {
                int row = (reg & 3) + 8 * (reg >> 2) + 4 * h;
                int t = t0 + wm * 64 + mi * 32 + row;
                float s = 1.f / (1.f + expf(-(accg[mi][reg] + gb)));
                sk2[(size_t)t * OUT_DIM + n] = f2bf((acck[mi][reg] + sb_) * (1.f - s));
                unsigned int pk = (unsigned int)f2bf(s);
                int idx = mi * 8 + (reg >> 1);
                if (reg & 1) sigp[idx] |= pk << 16;
                else         sigp[idx]  = pk;
            }
        }
    }

    // ---- mix phase, K = 2048, 64 tiles of BK=32 ----
    #pragma unroll
    for (int mi = 0; mi < 2; mi++)
        #pragma unroll
        for (int e = 0; e < 16; e++) accg[mi][e] = 0.f;
    {
        asm volatile("s_waitcnt vmcnt(0)" ::: "memory");
        __builtin_amdgcn_s_barrier();

        for (int t = 0; t < 64; ++t) {
            if (t + 1 < 64) STAGE_M((t + 1) & 1, (t + 1) * 32);
            const unsigned short* As = &L[(t & 1) * 8192];
            const unsigned short* Bs = As + 4096;
            #pragma unroll
            for (int kh = 0; kh < 2; kh++) {
                const int so = ((kh * 2 + h + srot) & 3) * 8;
                bf16x8 af0 = *(const bf16x8*)&As[(wm * 64 + l31) * 32 + so];
                bf16x8 af1 = *(const bf16x8*)&As[(wm * 64 + 32 + l31) * 32 + so];
                bf16x8 bf  = *(const bf16x8*)&Bs[(wn * 32 + l31) * 32 + so];
                __builtin_amdgcn_s_setprio(1);
                accg[0] = __builtin_amdgcn_mfma_f32_32x32x16_bf16(af0, bf, accg[0], 0, 0, 0);
                accg[1] = __builtin_amdgcn_mfma_f32_32x32x16_bf16(af1, bf, accg[1], 0, 0, 0);
                __builtin_amdgcn_s_setprio(0);
            }
            asm volatile("s_waitcnt vmcnt(0)" ::: "memory");
            __builtin_amdgcn_s_barrier();
        }
#undef STAGE_M
    }

    {
        const int n = n0 + wn * 32 + l31;
        const float mb_ = mix_b[n];
        #pragma unroll
        for (int mi = 0; mi < 2; mi++) {
            #pragma unroll
            for (int reg = 0; reg < 16; reg++) {
                int row = (reg & 3) + 8 * (reg >> 2) + 4 * h;
                int t = t0 + wm * 64 + mi * 32 + row;
                unsigned int u = sigp[mi * 8 + (reg >> 1)];
                float sig = bf2f((unsigned short)((reg & 1) ? (u >> 16) : (u & 0xffff)));
                zg[(size_t)t * OUT_DIM + n] = f2bf((accg[mi][reg] + mb_) * sig);
            }
        }
    }
}

// ---------------- G3: LayerNorm + residual (bf16 in, fp32 out) --------------------------------
__global__ __launch_bounds__(256) void g3_ln(const unsigned short* __restrict__ zg,
        const unsigned short* __restrict__ sk2, float* __restrict__ out)
{
    __shared__ float sb[4], qb[4];
    __shared__ float mu_s, rstd_s;
    const int t = blockIdx.x;
    const int tid = threadIdx.x;
    ushort4 zu = *(const ushort4*)&zg [(size_t)t * OUT_DIM + tid * 4];
    ushort4 su = *(const ushort4*)&sk2[(size_t)t * OUT_DIM + tid * 4];
    float z0 = bf2f(zu.x), z1 = bf2f(zu.y), z2 = bf2f(zu.z), z3 = bf2f(zu.w);
    float s0 = bf2f(su.x), s1 = bf2f(su.y), s2 = bf2f(su.z), s3 = bf2f(su.w);
    float s = z0 + z1 + z2 + z3;
    float q = z0*z0 + z1*z1 + z2*z2 + z3*z3;
    #pragma unroll
    for (int off = 32; off > 0; off >>= 1) {
        s += __shfl_down(s, off, 64);
        q += __shfl_down(q, off, 64);
    }
    int wid = tid >> 6;
    if ((tid & 63) == 0) { sb[wid] = s; qb[wid] = q; }
    __syncthreads();
    if (tid == 0) {
        float S = sb[0] + sb[1] + sb[2] + sb[3];
        float Q = qb[0] + qb[1] + qb[2] + qb[3];
        float mu = S * (1.f / 1024.f);
        float var = Q * (1.f / 1024.f) - mu * mu;
        mu_s = mu; rstd_s = rsqrtf(var + 1e-5f);
    }
    __syncthreads();
    float mu = mu_s, rs = rstd_s;
    float4 o;
    o.x = (z0 - mu) * rs + s0;
    o.y = (z1 - mu) * rs + s1;
    o.z = (z2 - mu) * rs + s2;
    o.w = (z3 - mu) * rs + s3;
    *(float4*)&out[(size_t)t * OUT_DIM + tid * 4] = o;
}

// ---------------- G4: final_state copy (planar re/im, guarded) --------------------------------
__global__ void g4_final(const float* __restrict__ fstate, float* __restrict__ out, int out_size)
{
    int i = blockIdx.x * blockDim.x + threadIdx.x;
    if (i >= 2048) return;
    long long base = (long long)T_DIM * OUT_DIM;
    if (base + i < (long long)out_size) out[base + i] = fstate[i];
}

extern "C" void kernel_launch(void* const* d_in, const int* in_sizes, int n_in,
                              void* d_out, int out_size, void* d_ws, size_t ws_size,
                              hipStream_t stream) {
    const float* x        = (const float*)d_in[0];
    const float* state_re = (const float*)d_in[1];
    const float* state_im = (const float*)d_in[2];
    const void*  startp   = d_in[3];
    const float* pre_w    = (const float*)d_in[5];
    const float* pre_b    = (const float*)d_in[6];
    const float* gi_w     = (const float*)d_in[7];
    const float* gi_b     = (const float*)d_in[8];
    const float* go_w     = (const float*)d_in[9];
    const float* go_b     = (const float*)d_in[10];
    const float* skip_w   = (const float*)d_in[11];
    const float* skip_b   = (const float*)d_in[12];
    const float* mix_w    = (const float*)d_in[13];
    const float* mix_b    = (const float*)d_in[14];
    const float* ffa_a    = (const float*)d_in[15];
    const float* ffa_b    = (const float*)d_in[16];

    float* ws = (float*)d_ws;
    float*          gxT    = ws;
    unsigned short* zinTb  = (unsigned short*)(ws + 524288);
    unsigned short* zinb   = (unsigned short*)(ws + 8912896);
    unsigned short* xb     = (unsigned short*)(ws + 17301504);
    unsigned short* gob    = (unsigned short*)(ws + 21495808);
    unsigned short* skb    = (unsigned short*)(ws + 22020096);
    unsigned short* mixb   = (unsigned short*)(ws + 22544384);
    unsigned short* zg     = (unsigned short*)(ws + 23592960);
    unsigned short* sk2    = (unsigned short*)(ws + 27787264);
    float*          fstate = ws + 31981568;
    unsigned char*  mask   = (unsigned char*)(ws + 31983616);
    unsigned short* pwb    = zg;            // borrow zg region pre-gA
    unsigned short* gwb    = zg + 65536;
    float* out = (float*)d_out;

    hipLaunchKernelGGL(c0_conv,  dim3(1536),    dim3(256),  0, stream, x, go_w, skip_w, mix_w, pre_w, gi_w,
                                                             startp, xb, gob, skb, mixb, pwb, gwb, mask);
    hipLaunchKernelGGL(k1_mfma,  dim3(256),     dim3(256),  0, stream, xb, pwb, gwb, pre_b, gi_b, gxT);
    hipLaunchKernelGGL(k2_scan,  dim3(1024),    dim3(128),  0, stream, gxT, mask, state_re, state_im, ffa_a, ffa_b, zinTb, fstate);
    hipLaunchKernelGGL(t3_tr,    dim3(32, 128), dim3(256),  0, stream, zinTb, zinb);
    hipLaunchKernelGGL(gA_gemm,  dim3(1024),    dim3(256),  0, stream, xb, zinb, gob, skb, mixb, go_b, skip_b, mix_b, zg, sk2);
    hipLaunchKernelGGL(g3_ln,    dim3(8192),    dim3(256),  0, stream, zg, sk2, out);
    hipLaunchKernelGGL(g4_final, dim3(8),       dim3(256),  0, stream, fstate, out, out_size);
}

// Round 3
// 271.199 us; speedup vs baseline: 1.1943x; 1.1943x over previous
//
#include <hip/hip_runtime.h>
#include <math.h>

#define T_DIM 8192
#define IN_DIM 1024
#define TRACE 64
#define CTX 16
#define OUT_DIM 1024
#define KMIX 2048

typedef __attribute__((ext_vector_type(8))) short bf16x8;
typedef __attribute__((ext_vector_type(4))) float f32x4;
typedef __attribute__((ext_vector_type(16))) float f32x16;

__device__ __forceinline__ unsigned short f2bf(float f) {
    unsigned int u = __float_as_uint(f);
    u = (u + 0x7FFFu + ((u >> 16) & 1u)) >> 16;
    return (unsigned short)u;
}
__device__ __forceinline__ float bf2f(unsigned short b) {
    return __uint_as_float(((unsigned int)b) << 16);
}

__device__ __forceinline__ void gl2lds16(const void* g, void* l) {
    __builtin_amdgcn_global_load_lds(
        (const __attribute__((address_space(1))) unsigned int*)g,
        (__attribute__((address_space(3))) unsigned int*)l,
        16, 0, 0);
}

// ---------------- ws layout (float offsets) ----------------
// gxT   fp32 [64][8192]      @ 0         (524288 f)
// zinTb bf16 [2048][8192]    @ 524288    (8388608 f)
// zinb  bf16 [8192][2048]    @ 8912896   (8388608 f)
// xb    bf16 [8192][1024]    @ 17301504  (4194304 f)
// gob   bf16 [1024][1024]    @ 21495808  (524288 f)
// skb   bf16 [1024][1024]    @ 22020096  (524288 f)
// mixb  bf16 [1024][2048]    @ 22544384  (1048576 f)
// zg    bf16 [8192][1024]    @ 23592960  (4194304 f)   [pwb/gwb borrow pre-gA]
// sk2   bf16 [8192][1024]    @ 27787264  (4194304 f)
// fstate fp32 [2048]         @ 31981568
// mask  u8   [8192]          @ 31983616  (2048 f)
// mask64 u64 [128]           @ 31985664  (256 f)

// ---------------- C0: fp32 -> bf16 conversions + start-mask normalize + bit-pack -------------
__global__ __launch_bounds__(256) void c0_conv(const float* __restrict__ x,
        const float* __restrict__ gw, const float* __restrict__ sw, const float* __restrict__ mw,
        const float* __restrict__ pw, const float* __restrict__ giw,
        const void* __restrict__ startp,
        unsigned short* __restrict__ xb, unsigned short* __restrict__ gob,
        unsigned short* __restrict__ skb, unsigned short* __restrict__ mixb,
        unsigned short* __restrict__ pwb, unsigned short* __restrict__ gwb,
        unsigned char* __restrict__ mask, unsigned long long* __restrict__ mask64)
{
    if (blockIdx.x == 0) {
        __shared__ int nonbool;
        int tid = threadIdx.x;
        if (tid == 0) nonbool = 0;
        __syncthreads();
        const unsigned int* wv = (const unsigned int*)startp;
        #pragma unroll
        for (int p = 0; p < 8; p++) {
            unsigned int a = wv[tid * 8 + p];
            if (a > 1u) nonbool = 1;
        }
        __syncthreads();
        if (nonbool) {
            const unsigned char* s8 = (const unsigned char*)startp;
            for (int i = tid; i < T_DIM; i += 256) mask[i] = (unsigned char)(s8[i] != 0);
        } else {
            const int* s32 = (const int*)startp;
            for (int i = tid; i < T_DIM; i += 256) mask[i] = (unsigned char)(s32[i] != 0);
        }
        __syncthreads();   // mask bytes visible block-wide; pack 64 bits/thread
        if (tid < 128) {
            unsigned long long wv2 = 0ull;
            int base = tid * 64;
            #pragma unroll 8
            for (int b2 = 0; b2 < 64; b2++)
                wv2 |= ((unsigned long long)(mask[base + b2] & 1)) << b2;
            mask64[tid] = wv2;
        }
    }
    const size_t QX = 2097152, QG = 262144, QS = 262144, QM = 524288, QP = 16384, QI = 16384;
    const size_t total = QX + QG + QS + QM + QP + QI;
    for (size_t q = (size_t)blockIdx.x * blockDim.x + threadIdx.x; q < total;
         q += (size_t)gridDim.x * blockDim.x) {
        const float* src; unsigned short* dst; size_t i;
        if (q < QX)                  { src = x;   dst = xb;   i = q; }
        else if (q < QX+QG)          { src = gw;  dst = gob;  i = q - QX; }
        else if (q < QX+QG+QS)       { src = sw;  dst = skb;  i = q - QX - QG; }
        else if (q < QX+QG+QS+QM)    { src = mw;  dst = mixb; i = q - QX - QG - QS; }
        else if (q < QX+QG+QS+QM+QP) { src = pw;  dst = pwb;  i = q - QX - QG - QS - QM; }
        else                         { src = giw; dst = gwb;  i = q - QX - QG - QS - QM - QP; }
        float4 v = *(const float4*)(src + i * 4);
        ushort4 o;
        o.x = f2bf(v.x); o.y = f2bf(v.y); o.z = f2bf(v.z); o.w = f2bf(v.w);
        *(ushort4*)(dst + i * 4) = o;
    }
}

// ---------------- K1: MFMA gated_x, 256 blocks of 32t x 128m, swizzled LDS --------------------
__global__ __launch_bounds__(256) void k1_mfma(const unsigned short* __restrict__ xb,
        const unsigned short* __restrict__ pwb, const unsigned short* __restrict__ gwb,
        const float* __restrict__ pre_b, const float* __restrict__ gi_b,
        float* __restrict__ gxT)
{
    __shared__ __align__(16) unsigned short As[1024];
    __shared__ __align__(16) unsigned short Bs[4096];
    __shared__ float sgE[64][33];

    const int tid = threadIdx.x;
    const int t0 = blockIdx.x * 32;
    const int lane = tid & 63, w = tid >> 6;
    const int quad = lane >> 4, l16 = lane & 15;
    const int r = tid >> 2, s4 = tid & 3;
    const int csw = (s4 - ((r >> 1) & 3)) & 3;

    f32x4 acc[2][2];
    const f32x4 zero4 = {0.f, 0.f, 0.f, 0.f};
    #pragma unroll
    for (int mi = 0; mi < 2; mi++)
        #pragma unroll
        for (int ni = 0; ni < 2; ni++) acc[mi][ni] = zero4;

    const int sfr = (quad + ((l16 >> 1) & 3)) & 3;

    for (int k0 = 0; k0 < IN_DIM; k0 += 32) {
        __syncthreads();
        if (tid < 128) {
            int ra = tid >> 2;
            int ca = ((tid & 3) - ((ra >> 1) & 3)) & 3;
            gl2lds16(xb + (size_t)(t0 + ra) * IN_DIM + k0 + ca * 8, As + tid * 8);
        }
        gl2lds16(pwb + (size_t)r * IN_DIM + k0 + csw * 8, Bs + tid * 8);
        gl2lds16(gwb + (size_t)r * IN_DIM + k0 + csw * 8, Bs + 2048 + tid * 8);
        asm volatile("s_waitcnt vmcnt(0)" ::: "memory");
        __syncthreads();
        bf16x8 af[2], bf[2];
        #pragma unroll
        for (int mi = 0; mi < 2; mi++)
            af[mi] = *(const bf16x8*)&As[(mi * 16 + l16) * 32 + sfr * 8];
        #pragma unroll
        for (int ni = 0; ni < 2; ni++)
            bf[ni] = *(const bf16x8*)&Bs[(w * 32 + ni * 16 + l16) * 32 + sfr * 8];
        #pragma unroll
        for (int mi = 0; mi < 2; mi++)
            #pragma unroll
            for (int ni = 0; ni < 2; ni++)
                acc[mi][ni] = __builtin_amdgcn_mfma_f32_16x16x32_bf16(af[mi], bf[ni], acc[mi][ni], 0, 0, 0);
    }

    if (w >= 2) {
        #pragma unroll
        for (int mi = 0; mi < 2; mi++)
            #pragma unroll
            for (int ni = 0; ni < 2; ni++) {
                int mg = (w - 2) * 32 + ni * 16 + l16;
                float gb = gi_b[mg];
                #pragma unroll
                for (int rr = 0; rr < 4; rr++) {
                    int tl = mi * 16 + quad * 4 + rr;
                    sgE[mg][tl] = 1.f / (1.f + expf(-(acc[mi][ni][rr] + gb)));
                }
            }
    }
    __syncthreads();
    if (w < 2) {
        #pragma unroll
        for (int mi = 0; mi < 2; mi++)
            #pragma unroll
            for (int ni = 0; ni < 2; ni++) {
                int mp = w * 32 + ni * 16 + l16;
                float pb = pre_b[mp];
                float4 o;
                float* po = &o.x;
                #pragma unroll
                for (int rr = 0; rr < 4; rr++) {
                    int tl = mi * 16 + quad * 4 + rr;
                    po[rr] = (acc[mi][ni][rr] + pb) * sgE[mp][tl];
                }
                *(float4*)&gxT[(size_t)mp * T_DIM + t0 + mi * 16 + quad * 4] = o;
            }
    }
}

// ---------------- K2: resettable complex scan; LDS-staged input AND output --------------------
// Round-3: the old version issued 128 scalar global loads/lane (stride-256B across the wave)
// plus 64 scalar byte loads of mask -> classic uncoalesced G13 violation. Now: gxT row (32KB)
// is staged into LDS with coalesced float4 loads (+1-per-64 pad -> conflict-free reads), and
// the reset mask arrives as one packed uint64 per lane. SB transpose buffer aliases gxs.
__global__ __launch_bounds__(128) void k2_scan(const float* __restrict__ gxT,
        const unsigned long long* __restrict__ mask64,
        const float* __restrict__ state_re, const float* __restrict__ state_im,
        const float* __restrict__ ffa_a, const float* __restrict__ ffa_b,
        unsigned short* __restrict__ zinTb, float* __restrict__ fstate)
{
    const int m = blockIdx.x >> 4;
    const int c = blockIdx.x & 15;
    const int j = threadIdx.x;
    __shared__ __align__(16) float gxs[8192 + 128];   // padded: idx = t + (t>>6)
    __shared__ float Br[128], Bi[128], Er[128], Ei[128];
    __shared__ unsigned char Rf[128];
    unsigned int* SB = (unsigned int*)gxs;            // reused after pass 2 (guarded by sync)

    const float am = -fabsf(ffa_a[m]);
    const float bc = ffa_b[c];
    const float er = expf(am);
    const float gr = er * cosf(bc);
    const float gi = er * sinf(bc);

    // ---- coalesced stage of the gxT row ----
    {
        const float4* gx4 = (const float4*)(gxT + (size_t)m * T_DIM);
        #pragma unroll
        for (int it = 0; it < 16; it++) {
            int g = it * 128 + j;
            float4 v = gx4[g];
            int t = g * 4;
            gxs[t     + ( t      >> 6)] = v.x;
            gxs[t + 1 + ((t + 1) >> 6)] = v.y;
            gxs[t + 2 + ((t + 2) >> 6)] = v.z;
            gxs[t + 3 + ((t + 3) >> 6)] = v.w;
        }
    }
    const unsigned long long mw = mask64[j];
    __syncthreads();

    const int lb = j * 65;   // lane-local base in padded gxs
    float sre = 0.f, sim = 0.f;
    #pragma unroll 16
    for (int i = 0; i < 64; i++) {
        if ((mw >> i) & 1ull) { sre = 0.f; sim = 0.f; }
        else { float tr_ = sre * gr - sim * gi; sim = sre * gi + sim * gr; sre = tr_; }
        sre += gxs[lb + i];
    }
    Br[j] = sre; Bi[j] = sim; Rf[j] = (mw != 0ull) ? 1 : 0;
    __syncthreads();
    if (j == 0) {
        float e64  = expf(64.f * am);
        float g64r = e64 * cosf(64.f * bc);
        float g64i = e64 * sinf(64.f * bc);
        float pr = state_re[m * CTX + c], pi = state_im[m * CTX + c];
        for (int q = 0; q < 128; q++) {
            Er[q] = pr; Ei[q] = pi;
            if (Rf[q]) { pr = Br[q]; pi = Bi[q]; }
            else {
                float nr = pr * g64r - pi * g64i + Br[q];
                pi       = pr * g64i + pi * g64r + Bi[q];
                pr = nr;
            }
        }
    }
    __syncthreads();
    sre = Er[j]; sim = Ei[j];
    unsigned int ore[32], oim[32];
    #pragma unroll
    for (int i = 0; i < 64; i++) {
        if ((mw >> i) & 1ull) { sre = 0.f; sim = 0.f; }
        else { float tr_ = sre * gr - sim * gi; sim = sre * gi + sim * gr; sre = tr_; }
        sre += gxs[lb + i];
        unsigned short hr = f2bf(sre), hi_ = f2bf(sim);
        if (i & 1) { ore[i >> 1] |= ((unsigned int)hr) << 16; oim[i >> 1] |= ((unsigned int)hi_) << 16; }
        else       { ore[i >> 1]  = hr;                        oim[i >> 1]  = hi_; }
    }
    if (j == 127) {
        int p = m * CTX + c;
        fstate[p]        = sre;
        fstate[1024 + p] = sim;
    }

    unsigned short* zreb = zinTb + (size_t)(m * 32 + c)      * T_DIM;
    unsigned short* zimb = zinTb + (size_t)(m * 32 + 16 + c) * T_DIM;

    __syncthreads();   // all gxs reads done before SB (alias) is written
    #pragma unroll
    for (int q = 0; q < 32; q++) SB[j * 33 + q] = ore[q];
    __syncthreads();
    #pragma unroll
    for (int it = 0; it < 8; it++) {
        int g = (it * 128 + j) * 4;
        int jj = g >> 5, qq = g & 31;
        uint4 v = *(uint4*)&SB[jj * 33 + qq];
        *(uint4*)(zreb + g * 2) = v;
    }
    __syncthreads();
    #pragma unroll
    for (int q = 0; q < 32; q++) SB[j * 33 + q] = oim[q];
    __syncthreads();
    #pragma unroll
    for (int it = 0; it < 8; it++) {
        int g = (it * 128 + j) * 4;
        int jj = g >> 5, qq = g & 31;
        uint4 v = *(uint4*)&SB[jj * 33 + qq];
        *(uint4*)(zimb + g * 2) = v;
    }
}

// ---------------- T3: transpose zinTb[k][t] -> zinb[t][k], 64x64 tiles -------------------------
__global__ __launch_bounds__(256) void t3_tr(const unsigned short* __restrict__ zinTb,
                                             unsigned short* __restrict__ zinb)
{
    __shared__ unsigned short S[64][72];
    const int k0 = blockIdx.x * 64, t0 = blockIdx.y * 64;
    const int tid = threadIdx.x;
    {
        int kr = tid >> 3, tc = (tid & 7) * 8;
        #pragma unroll
        for (int p = 0; p < 2; p++) {
            int k = kr + p * 32;
            ushort4 a = *(const ushort4*)&zinTb[(size_t)(k0 + k) * T_DIM + t0 + tc];
            ushort4 b = *(const ushort4*)&zinTb[(size_t)(k0 + k) * T_DIM + t0 + tc + 4];
            *(ushort4*)&S[k][tc]     = a;
            *(ushort4*)&S[k][tc + 4] = b;
        }
    }
    __syncthreads();
    {
        int tr = tid >> 3, kc = (tid & 7) * 8;
        #pragma unroll
        for (int p = 0; p < 2; p++) {
            int t = tr + p * 32;
            ushort4 o1, o2;
            o1.x = S[kc+0][t]; o1.y = S[kc+1][t]; o1.z = S[kc+2][t]; o1.w = S[kc+3][t];
            o2.x = S[kc+4][t]; o2.y = S[kc+5][t]; o2.z = S[kc+6][t]; o2.w = S[kc+7][t];
            *(ushort4*)&zinb[(size_t)(t0 + t) * KMIX + k0 + kc]     = o1;
            *(ushort4*)&zinb[(size_t)(t0 + t) * KMIX + k0 + kc + 4] = o2;
        }
    }
}

// ---------------- GA: 256x128 tile, 8 waves, BK=32, triple-buffered depth-2 prefetch ----------
// (round-1 version: best measured gA = 88 us. Round-2's 128x64/4-block variant regressed to
// 119 us: smaller tiles doubled FETCH/WRITE and raised LDS bytes/MFMA; TLP didn't convert.)
__global__ __launch_bounds__(512, 2) void gA_gemm(
        const unsigned short* __restrict__ xb,   const unsigned short* __restrict__ zinb,
        const unsigned short* __restrict__ gob,  const unsigned short* __restrict__ skb,
        const unsigned short* __restrict__ mixb,
        const float* __restrict__ go_b, const float* __restrict__ skip_b, const float* __restrict__ mix_b,
        unsigned short* __restrict__ zg, unsigned short* __restrict__ sk2)
{
    __shared__ __align__(16) unsigned short L[49152];   // 3 buffers x (A 8192 | B 4096 | C 4096)
    const int tid = threadIdx.x;
    const int b = blockIdx.x;
    const int xcd = b & 7, q = b >> 3;                  // q in [0,32)
    const int t0 = (xcd * 4 + (q >> 3)) * 256;          // 32 t-tiles of 256 (XCD-contiguous)
    const int n0 = (q & 7) * 128;                       // 8 n-tiles of 128

    const int lane = tid & 63, w = tid >> 6;            // 8 waves
    const int wm = w >> 1, wn = w & 1;                  // 4 x 2 wave grid, wave tile 64x64
    const int l31 = lane & 31, h = lane >> 5;
    const int r = tid >> 2;                             // [0,128)
    const int csw = ((tid & 3) - ((r >> 1) & 3)) & 3;   // staging chunk permutation
    const int c8 = csw * 8;
    const int srot = (l31 >> 1) & 3;                    // fragment de-swizzle rotation
    const int dst8 = tid * 8;

    f32x16 accg[2][2], acck[2][2];
    #pragma unroll
    for (int mi = 0; mi < 2; mi++)
        #pragma unroll
        for (int ni = 0; ni < 2; ni++)
            #pragma unroll
            for (int e = 0; e < 16; e++) { accg[mi][ni][e] = 0.f; acck[mi][ni][e] = 0.f; }

    // ---- fused phase: go + skip (shared A = xb), K = 1024, 32 tiles of BK=32 ----
    {
        const unsigned short* gA0 = xb  + (size_t)(t0 + r)       * IN_DIM + c8;
        const unsigned short* gA1 = xb  + (size_t)(t0 + 128 + r) * IN_DIM + c8;
        const unsigned short* gB0 = gob + (size_t)(n0 + r)       * IN_DIM + c8;
        const unsigned short* gC0 = skb + (size_t)(n0 + r)       * IN_DIM + c8;

#define STAGE_F(bufi, kof) do {                         \
        unsigned short* _b = &L[(bufi) * 16384];        \
        gl2lds16(gA0 + (kof), _b + dst8);               \
        gl2lds16(gA1 + (kof), _b + 4096 + dst8);        \
        gl2lds16(gB0 + (kof), _b + 8192 + dst8);        \
        gl2lds16(gC0 + (kof), _b + 12288 + dst8);       \
    } while (0)

        STAGE_F(0, 0);
        STAGE_F(1, 32);
        asm volatile("s_waitcnt vmcnt(4)" ::: "memory");
        __builtin_amdgcn_s_barrier();

        int cur = 0, nx2 = 2;
        for (int t = 0; t < 32; ++t) {
            const unsigned short* As = &L[cur * 16384];
            const unsigned short* Bs = As + 8192;
            const unsigned short* Cs = As + 12288;
            const bool st = (t + 2 < 32);
            #pragma unroll
            for (int kh = 0; kh < 2; kh++) {
                const int so = ((kh * 2 + h + srot) & 3) * 8;
                bf16x8 af[2], bg[2], bk[2];
                #pragma unroll
                for (int mi = 0; mi < 2; mi++)
                    af[mi] = *(const bf16x8*)&As[(wm * 64 + mi * 32 + l31) * 32 + so];
                #pragma unroll
                for (int ni = 0; ni < 2; ni++) {
                    bg[ni] = *(const bf16x8*)&Bs[(wn * 64 + ni * 32 + l31) * 32 + so];
                    bk[ni] = *(const bf16x8*)&Cs[(wn * 64 + ni * 32 + l31) * 32 + so];
                }
                if (kh == 0 && st) STAGE_F(nx2, (t + 2) * 32);
                __builtin_amdgcn_s_setprio(1);
                #pragma unroll
                for (int mi = 0; mi < 2; mi++)
                    #pragma unroll
                    for (int ni = 0; ni < 2; ni++) {
                        accg[mi][ni] = __builtin_amdgcn_mfma_f32_32x32x16_bf16(af[mi], bg[ni], accg[mi][ni], 0, 0, 0);
                        acck[mi][ni] = __builtin_amdgcn_mfma_f32_32x32x16_bf16(af[mi], bk[ni], acck[mi][ni], 0, 0, 0);
                    }
                __builtin_amdgcn_s_setprio(0);
            }
            if (st) { asm volatile("s_waitcnt vmcnt(4)" ::: "memory"); }
            else    { asm volatile("s_waitcnt vmcnt(0)" ::: "memory"); }
            __builtin_amdgcn_s_barrier();
            cur = (cur == 2) ? 0 : cur + 1;
            nx2 = (nx2 == 2) ? 0 : nx2 + 1;
        }
#undef STAGE_F
    }

    // sigmoid (packed bf16 pairs) + sk2 write
    unsigned int sigp[32];
    #pragma unroll
    for (int mi = 0; mi < 2; mi++)
        #pragma unroll
        for (int ni = 0; ni < 2; ni++) {
            int n = n0 + wn * 64 + ni * 32 + l31;
            float gb = go_b[n];
            float sb_ = skip_b[n];
            #pragma unroll
            for (int reg = 0; reg < 16; reg++) {
                int row = (reg & 3) + 8 * (reg >> 2) + 4 * h;
                int t = t0 + wm * 64 + mi * 32 + row;
                float s = 1.f / (1.f + expf(-(accg[mi][ni][reg] + gb)));
                sk2[(size_t)t * OUT_DIM + n] = f2bf((acck[mi][ni][reg] + sb_) * (1.f - s));
                unsigned int pk = (unsigned int)f2bf(s);
                int idx = (mi * 2 + ni) * 8 + (reg >> 1);
                if (reg & 1) sigp[idx] |= pk << 16;
                else         sigp[idx]  = pk;
            }
        }

    // ---- mix phase, K = 2048, 64 tiles of BK=32 ----
    #pragma unroll
    for (int mi = 0; mi < 2; mi++)
        #pragma unroll
        for (int ni = 0; ni < 2; ni++)
            #pragma unroll
            for (int e = 0; e < 16; e++) accg[mi][ni][e] = 0.f;
    {
        const unsigned short* mA0 = zinb + (size_t)(t0 + r)       * KMIX + c8;
        const unsigned short* mA1 = zinb + (size_t)(t0 + 128 + r) * KMIX + c8;
        const unsigned short* mB0 = mixb + (size_t)(n0 + r)       * KMIX + c8;

#define STAGE_M(bufi, kof) do {                         \
        unsigned short* _b = &L[(bufi) * 16384];        \
        gl2lds16(mA0 + (kof), _b + dst8);               \
        gl2lds16(mA1 + (kof), _b + 4096 + dst8);        \
        gl2lds16(mB0 + (kof), _b + 8192 + dst8);        \
    } while (0)

        STAGE_M(0, 0);
        STAGE_M(1, 32);
        asm volatile("s_waitcnt vmcnt(3)" ::: "memory");
        __builtin_amdgcn_s_barrier();

        int cur = 0, nx2 = 2;
        for (int t = 0; t < 64; ++t) {
            const unsigned short* As = &L[cur * 16384];
            const unsigned short* Bs = As + 8192;
            const bool st = (t + 2 < 64);
            #pragma unroll
            for (int kh = 0; kh < 2; kh++) {
                const int so = ((kh * 2 + h + srot) & 3) * 8;
                bf16x8 af[2], bf[2];
                #pragma unroll
                for (int mi = 0; mi < 2; mi++)
                    af[mi] = *(const bf16x8*)&As[(wm * 64 + mi * 32 + l31) * 32 + so];
                #pragma unroll
                for (int ni = 0; ni < 2; ni++)
                    bf[ni] = *(const bf16x8*)&Bs[(wn * 64 + ni * 32 + l31) * 32 + so];
                if (kh == 0 && st) STAGE_M(nx2, (t + 2) * 32);
                __builtin_amdgcn_s_setprio(1);
                #pragma unroll
                for (int mi = 0; mi < 2; mi++)
                    #pragma unroll
                    for (int ni = 0; ni < 2; ni++)
                        accg[mi][ni] = __builtin_amdgcn_mfma_f32_32x32x16_bf16(af[mi], bf[ni], accg[mi][ni], 0, 0, 0);
                __builtin_amdgcn_s_setprio(0);
            }
            if (st) { asm volatile("s_waitcnt vmcnt(3)" ::: "memory"); }
            else    { asm volatile("s_waitcnt vmcnt(0)" ::: "memory"); }
            __builtin_amdgcn_s_barrier();
            cur = (cur == 2) ? 0 : cur + 1;
            nx2 = (nx2 == 2) ? 0 : nx2 + 1;
        }
#undef STAGE_M
    }

    #pragma unroll
    for (int mi = 0; mi < 2; mi++)
        #pragma unroll
        for (int ni = 0; ni < 2; ni++) {
            int n = n0 + wn * 64 + ni * 32 + l31;
            float mb_ = mix_b[n];
            #pragma unroll
            for (int reg = 0; reg < 16; reg++) {
                int row = (reg & 3) + 8 * (reg >> 2) + 4 * h;
                int t = t0 + wm * 64 + mi * 32 + row;
                unsigned int u = sigp[(mi * 2 + ni) * 8 + (reg >> 1)];
                float sig = bf2f((unsigned short)((reg & 1) ? (u >> 16) : (u & 0xffff)));
                zg[(size_t)t * OUT_DIM + n] = f2bf((accg[mi][ni][reg] + mb_) * sig);
            }
        }
}

// ---------------- G3: LayerNorm + residual (bf16 in, fp32 out) + final_state copy ------------
__global__ __launch_bounds__(256) void g3_ln(const unsigned short* __restrict__ zg,
        const unsigned short* __restrict__ sk2, const float* __restrict__ fstate,
        float* __restrict__ out, int out_size)
{
    __shared__ float sb[4], qb[4];
    __shared__ float mu_s, rstd_s;
    const int t = blockIdx.x;
    const int tid = threadIdx.x;
    ushort4 zu = *(const ushort4*)&zg [(size_t)t * OUT_DIM + tid * 4];
    ushort4 su = *(const ushort4*)&sk2[(size_t)t * OUT_DIM + tid * 4];
    float z0 = bf2f(zu.x), z1 = bf2f(zu.y), z2 = bf2f(zu.z), z3 = bf2f(zu.w);
    float s0 = bf2f(su.x), s1 = bf2f(su.y), s2 = bf2f(su.z), s3 = bf2f(su.w);
    float s = z0 + z1 + z2 + z3;
    float q = z0*z0 + z1*z1 + z2*z2 + z3*z3;
    #pragma unroll
    for (int off = 32; off > 0; off >>= 1) {
        s += __shfl_down(s, off, 64);
        q += __shfl_down(q, off, 64);
    }
    int wid = tid >> 6;
    if ((tid & 63) == 0) { sb[wid] = s; qb[wid] = q; }
    __syncthreads();
    if (tid == 0) {
        float S = sb[0] + sb[1] + sb[2] + sb[3];
        float Q = qb[0] + qb[1] + qb[2] + qb[3];
        float mu = S * (1.f / 1024.f);
        float var = Q * (1.f / 1024.f) - mu * mu;
        mu_s = mu; rstd_s = rsqrtf(var + 1e-5f);
    }
    __syncthreads();
    float mu = mu_s, rs = rstd_s;
    float4 o;
    o.x = (z0 - mu) * rs + s0;
    o.y = (z1 - mu) * rs + s1;
    o.z = (z2 - mu) * rs + s2;
    o.w = (z3 - mu) * rs + s3;
    *(float4*)&out[(size_t)t * OUT_DIM + tid * 4] = o;

    if (t < 8) {   // folded g4: final_state copy
        int i = t * 256 + tid;
        long long base = (long long)T_DIM * OUT_DIM;
        if (base + i < (long long)out_size) out[base + i] = fstate[i];
    }
}

extern "C" void kernel_launch(void* const* d_in, const int* in_sizes, int n_in,
                              void* d_out, int out_size, void* d_ws, size_t ws_size,
                              hipStream_t stream) {
    const float* x        = (const float*)d_in[0];
    const float* state_re = (const float*)d_in[1];
    const float* state_im = (const float*)d_in[2];
    const void*  startp   = d_in[3];
    const float* pre_w    = (const float*)d_in[5];
    const float* pre_b    = (const float*)d_in[6];
    const float* gi_w     = (const float*)d_in[7];
    const float* gi_b     = (const float*)d_in[8];
    const float* go_w     = (const float*)d_in[9];
    const float* go_b     = (const float*)d_in[10];
    const float* skip_w   = (const float*)d_in[11];
    const float* skip_b   = (const float*)d_in[12];
    const float* mix_w    = (const float*)d_in[13];
    const float* mix_b    = (const float*)d_in[14];
    const float* ffa_a    = (const float*)d_in[15];
    const float* ffa_b    = (const float*)d_in[16];

    float* ws = (float*)d_ws;
    float*          gxT    = ws;
    unsigned short* zinTb  = (unsigned short*)(ws + 524288);
    unsigned short* zinb   = (unsigned short*)(ws + 8912896);
    unsigned short* xb     = (unsigned short*)(ws + 17301504);
    unsigned short* gob    = (unsigned short*)(ws + 21495808);
    unsigned short* skb    = (unsigned short*)(ws + 22020096);
    unsigned short* mixb   = (unsigned short*)(ws + 22544384);
    unsigned short* zg     = (unsigned short*)(ws + 23592960);
    unsigned short* sk2    = (unsigned short*)(ws + 27787264);
    float*          fstate = ws + 31981568;
    unsigned char*  mask   = (unsigned char*)(ws + 31983616);
    unsigned long long* mask64 = (unsigned long long*)(ws + 31985664);
    unsigned short* pwb    = zg;            // borrow zg region pre-gA
    unsigned short* gwb    = zg + 65536;
    float* out = (float*)d_out;

    hipLaunchKernelGGL(c0_conv,  dim3(1536),    dim3(256),  0, stream, x, go_w, skip_w, mix_w, pre_w, gi_w,
                                                             startp, xb, gob, skb, mixb, pwb, gwb, mask, mask64);
    hipLaunchKernelGGL(k1_mfma,  dim3(256),     dim3(256),  0, stream, xb, pwb, gwb, pre_b, gi_b, gxT);
    hipLaunchKernelGGL(k2_scan,  dim3(1024),    dim3(128),  0, stream, gxT, mask64, state_re, state_im, ffa_a, ffa_b, zinTb, fstate);
    hipLaunchKernelGGL(t3_tr,    dim3(32, 128), dim3(256),  0, stream, zinTb, zinb);
    hipLaunchKernelGGL(gA_gemm,  dim3(256),     dim3(512),  0, stream, xb, zinb, gob, skb, mixb, go_b, skip_b, mix_b, zg, sk2);
    hipLaunchKernelGGL(g3_ln,    dim3(8192),    dim3(256),  0, stream, zg, sk2, fstate, out, out_size);
}

// Round 5
// 263.363 us; speedup vs baseline: 1.2298x; 1.0298x over previous
//
#include <hip/hip_runtime.h>
#include <math.h>

#define T_DIM 8192
#define IN_DIM 1024
#define TRACE 64
#define CTX 16
#define OUT_DIM 1024
#define KMIX 2048

typedef __attribute__((ext_vector_type(8))) short bf16x8;
typedef __attribute__((ext_vector_type(4))) float f32x4;
typedef __attribute__((ext_vector_type(16))) float f32x16;

__device__ __forceinline__ unsigned short f2bf(float f) {
    unsigned int u = __float_as_uint(f);
    u = (u + 0x7FFFu + ((u >> 16) & 1u)) >> 16;
    return (unsigned short)u;
}
__device__ __forceinline__ float bf2f(unsigned short b) {
    return __uint_as_float(((unsigned int)b) << 16);
}

__device__ __forceinline__ void gl2lds16(const void* g, void* l) {
    __builtin_amdgcn_global_load_lds(
        (const __attribute__((address_space(1))) unsigned int*)g,
        (__attribute__((address_space(3))) unsigned int*)l,
        16, 0, 0);
}

// ---------------- ws layout (float offsets) ----------------
// gxT   fp32 [64][8192]      @ 0         (524288 f)
// zinb  bf16 [8192][2048]    @ 8912896   (8388608 f)   k-order: k' = m*32 + 2c + (0 re/1 im)
// xb    bf16 [8192][1024]    @ 17301504  (4194304 f)
// gob   bf16 [1024][1024]    @ 21495808  (524288 f)
// skb   bf16 [1024][1024]    @ 22020096  (524288 f)
// mixb  bf16 [1024][2048]    @ 22544384  (1048576 f)   same permuted k-order as zinb
// zg    bf16 [8192][1024]    @ 23592960  (4194304 f)   [pwb/gwb borrow pre-gA]
// sk2   bf16 [8192][1024]    @ 27787264  (4194304 f)
// fstate fp32 [2048]         @ 31981568
// mask  u8   [8192]          @ 31983616  (2048 f)
// mask64 u64 [128]           @ 31985664  (256 f)

// ---------------- C0: fp32 -> bf16 conversions + start-mask normalize + bit-pack -------------
// Reference z_in flattening is k = m*32 + p*16 + c (concat along CTX axis!). mixb gets the
// re/im-interleaved permutation k' = m*32 + 2c + p  <-  k = m*32 + p*16 + c, matching k2's
// packed-uint output order, so gA's GEMM is order-consistent.
__global__ __launch_bounds__(256) void c0_conv(const float* __restrict__ x,
        const float* __restrict__ gw, const float* __restrict__ sw, const float* __restrict__ mw,
        const float* __restrict__ pw, const float* __restrict__ giw,
        const void* __restrict__ startp,
        unsigned short* __restrict__ xb, unsigned short* __restrict__ gob,
        unsigned short* __restrict__ skb, unsigned short* __restrict__ mixb,
        unsigned short* __restrict__ pwb, unsigned short* __restrict__ gwb,
        unsigned char* __restrict__ mask, unsigned long long* __restrict__ mask64)
{
    if (blockIdx.x == 0) {
        __shared__ int nonbool;
        int tid = threadIdx.x;
        if (tid == 0) nonbool = 0;
        __syncthreads();
        const unsigned int* wv = (const unsigned int*)startp;
        #pragma unroll
        for (int p = 0; p < 8; p++) {
            unsigned int a = wv[tid * 8 + p];
            if (a > 1u) nonbool = 1;
        }
        __syncthreads();
        if (nonbool) {
            const unsigned char* s8 = (const unsigned char*)startp;
            for (int i = tid; i < T_DIM; i += 256) mask[i] = (unsigned char)(s8[i] != 0);
        } else {
            const int* s32 = (const int*)startp;
            for (int i = tid; i < T_DIM; i += 256) mask[i] = (unsigned char)(s32[i] != 0);
        }
        __syncthreads();   // mask bytes visible block-wide; pack 64 bits/thread
        if (tid < 128) {
            unsigned long long wv2 = 0ull;
            int base = tid * 64;
            #pragma unroll 8
            for (int b2 = 0; b2 < 64; b2++)
                wv2 |= ((unsigned long long)(mask[base + b2] & 1)) << b2;
            mask64[tid] = wv2;
        }
    }
    // part A: straight conversions (x, go_w, skip_w, pre_w, gi_w)
    const size_t QX = 2097152, QG = 262144, QS = 262144, QP = 16384, QI = 16384;
    const size_t totalA = QX + QG + QS + QP + QI;   // 2654208
    for (size_t q = (size_t)blockIdx.x * blockDim.x + threadIdx.x; q < totalA;
         q += (size_t)gridDim.x * blockDim.x) {
        const float* src; unsigned short* dst; size_t i;
        if (q < QX)               { src = x;   dst = xb;   i = q; }
        else if (q < QX+QG)       { src = gw;  dst = gob;  i = q - QX; }
        else if (q < QX+QG+QS)    { src = sw;  dst = skb;  i = q - QX - QG; }
        else if (q < QX+QG+QS+QP) { src = pw;  dst = pwb;  i = q - QX - QG - QS; }
        else                      { src = giw; dst = gwb;  i = q - QX - QG - QS - QP; }
        float4 v = *(const float4*)(src + i * 4);
        ushort4 o;
        o.x = f2bf(v.x); o.y = f2bf(v.y); o.z = f2bf(v.z); o.w = f2bf(v.w);
        *(ushort4*)(dst + i * 4) = o;
    }
    // part B: mix_w with k-permutation (coalesced reads, strided 2B writes)
    // k = mm*32 + p*16 + cc  ->  k' = mm*32 + 2*cc + p
    const size_t QM = 524288;
    for (size_t q = (size_t)blockIdx.x * blockDim.x + threadIdx.x; q < QM;
         q += (size_t)gridDim.x * blockDim.x) {
        float4 v = *(const float4*)(mw + q * 4);
        int flat = (int)(q * 4);
        int n  = flat >> 11;
        int kk = flat & 2047;
        int mm = kk >> 5;
        int w_ = kk & 31;
        int p  = w_ >> 4;
        int cc = w_ & 15;            // multiple of 4 (flat is x4)
        int kb = (n << 11) + mm * 32 + (cc << 1) + p;
        mixb[kb]     = f2bf(v.x);
        mixb[kb + 2] = f2bf(v.y);
        mixb[kb + 4] = f2bf(v.z);
        mixb[kb + 6] = f2bf(v.w);
    }
}

// ---------------- K1: MFMA gated_x, 256 blocks of 32t x 128m, swizzled LDS --------------------
__global__ __launch_bounds__(256) void k1_mfma(const unsigned short* __restrict__ xb,
        const unsigned short* __restrict__ pwb, const unsigned short* __restrict__ gwb,
        const float* __restrict__ pre_b, const float* __restrict__ gi_b,
        float* __restrict__ gxT)
{
    __shared__ __align__(16) unsigned short As[1024];
    __shared__ __align__(16) unsigned short Bs[4096];
    __shared__ float sgE[64][33];

    const int tid = threadIdx.x;
    const int t0 = blockIdx.x * 32;
    const int lane = tid & 63, w = tid >> 6;
    const int quad = lane >> 4, l16 = lane & 15;
    const int r = tid >> 2, s4 = tid & 3;
    const int csw = (s4 - ((r >> 1) & 3)) & 3;

    f32x4 acc[2][2];
    const f32x4 zero4 = {0.f, 0.f, 0.f, 0.f};
    #pragma unroll
    for (int mi = 0; mi < 2; mi++)
        #pragma unroll
        for (int ni = 0; ni < 2; ni++) acc[mi][ni] = zero4;

    const int sfr = (quad + ((l16 >> 1) & 3)) & 3;

    for (int k0 = 0; k0 < IN_DIM; k0 += 32) {
        __syncthreads();
        if (tid < 128) {
            int ra = tid >> 2;
            int ca = ((tid & 3) - ((ra >> 1) & 3)) & 3;
            gl2lds16(xb + (size_t)(t0 + ra) * IN_DIM + k0 + ca * 8, As + tid * 8);
        }
        gl2lds16(pwb + (size_t)r * IN_DIM + k0 + csw * 8, Bs + tid * 8);
        gl2lds16(gwb + (size_t)r * IN_DIM + k0 + csw * 8, Bs + 2048 + tid * 8);
        asm volatile("s_waitcnt vmcnt(0)" ::: "memory");
        __syncthreads();
        bf16x8 af[2], bf[2];
        #pragma unroll
        for (int mi = 0; mi < 2; mi++)
            af[mi] = *(const bf16x8*)&As[(mi * 16 + l16) * 32 + sfr * 8];
        #pragma unroll
        for (int ni = 0; ni < 2; ni++)
            bf[ni] = *(const bf16x8*)&Bs[(w * 32 + ni * 16 + l16) * 32 + sfr * 8];
        #pragma unroll
        for (int mi = 0; mi < 2; mi++)
            #pragma unroll
            for (int ni = 0; ni < 2; ni++)
                acc[mi][ni] = __builtin_amdgcn_mfma_f32_16x16x32_bf16(af[mi], bf[ni], acc[mi][ni], 0, 0, 0);
    }

    if (w >= 2) {
        #pragma unroll
        for (int mi = 0; mi < 2; mi++)
            #pragma unroll
            for (int ni = 0; ni < 2; ni++) {
                int mg = (w - 2) * 32 + ni * 16 + l16;
                float gb = gi_b[mg];
                #pragma unroll
                for (int rr = 0; rr < 4; rr++) {
                    int tl = mi * 16 + quad * 4 + rr;
                    sgE[mg][tl] = 1.f / (1.f + expf(-(acc[mi][ni][rr] + gb)));
                }
            }
    }
    __syncthreads();
    if (w < 2) {
        #pragma unroll
        for (int mi = 0; mi < 2; mi++)
            #pragma unroll
            for (int ni = 0; ni < 2; ni++) {
                int mp = w * 32 + ni * 16 + l16;
                float pb = pre_b[mp];
                float4 o;
                float* po = &o.x;
                #pragma unroll
                for (int rr = 0; rr < 4; rr++) {
                    int tl = mi * 16 + quad * 4 + rr;
                    po[rr] = (acc[mi][ni][rr] + pb) * sgE[mp][tl];
                }
                *(float4*)&gxT[(size_t)mp * T_DIM + t0 + mi * 16 + quad * 4] = o;
            }
    }
}

// ---------------- K2: resettable complex scan, direct zinb[t][k'] output ----------------------
// One block per m (64 blocks x 1024 threads). thread = (c = tid&15, j = tid>>4); each thread
// scans a 128-t chunk for its (m,c). gxT row staged ONCE per block (was 16x re-read).
// Output: packed uint (re | im<<16) at k' = m*32 + 2c -> 16 c-lanes form exact 64B segments.
// This kills the t3 transpose kernel (64MB HBM round-trip) entirely.
__global__ __launch_bounds__(1024, 1) void k2_scan(const float* __restrict__ gxT,
        const unsigned long long* __restrict__ mask64,
        const float* __restrict__ state_re, const float* __restrict__ state_im,
        const float* __restrict__ ffa_a, const float* __restrict__ ffa_b,
        unsigned short* __restrict__ zinb, float* __restrict__ fstate)
{
    const int m = blockIdx.x;
    const int tid = threadIdx.x;
    const int c = tid & 15, j = tid >> 4;      // j in [0,64), 128-t chunk per thread
    __shared__ __align__(16) float gxs[8192 + 128];   // padded: idx = t + (t>>6)
    __shared__ float Br[16][65], Bi[16][65], Er[16][65], Ei[16][65];
    __shared__ unsigned char Rf[16][65];

    const float am = -fabsf(ffa_a[m]);
    const float bc = ffa_b[c];
    const float er = expf(am);
    const float gr = er * cosf(bc);
    const float gi = er * sinf(bc);

    // ---- coalesced one-time stage of the gxT row ----
    {
        const float4* gx4 = (const float4*)(gxT + (size_t)m * T_DIM);
        #pragma unroll
        for (int it = 0; it < 2; it++) {
            int g = it * 1024 + tid;
            float4 v = gx4[g];
            int t = g * 4;
            gxs[t     + ( t      >> 6)] = v.x;
            gxs[t + 1 + ((t + 1) >> 6)] = v.y;
            gxs[t + 2 + ((t + 2) >> 6)] = v.z;
            gxs[t + 3 + ((t + 3) >> 6)] = v.w;
        }
    }
    const unsigned long long mw0 = mask64[j * 2];
    const unsigned long long mw1 = mask64[j * 2 + 1];
    __syncthreads();

    const int lb = j * 130;   // padded base of this thread's 128-t chunk
    // ---- pass 1: chunk summary (scan from zero) ----
    float sre = 0.f, sim = 0.f;
    #pragma unroll 8
    for (int i = 0; i < 64; i++) {
        if ((mw0 >> i) & 1ull) { sre = 0.f; sim = 0.f; }
        else { float tr_ = sre * gr - sim * gi; sim = sre * gi + sim * gr; sre = tr_; }
        sre += gxs[lb + i];
    }
    #pragma unroll 8
    for (int i = 0; i < 64; i++) {
        if ((mw1 >> i) & 1ull) { sre = 0.f; sim = 0.f; }
        else { float tr_ = sre * gr - sim * gi; sim = sre * gi + sim * gr; sre = tr_; }
        sre += gxs[lb + 65 + i];
    }
    Br[c][j] = sre; Bi[c][j] = sim; Rf[c][j] = ((mw0 | mw1) != 0ull) ? 1 : 0;
    __syncthreads();

    // ---- serial summary scan: 16 threads, one per c ----
    if (tid < 16) {
        const int cc = tid;
        float b2 = 128.f * ffa_b[cc];
        float e128 = expf(128.f * am);
        float gRr = e128 * cosf(b2);
        float gRi = e128 * sinf(b2);
        float pr = state_re[m * CTX + cc], pi = state_im[m * CTX + cc];
        for (int q2 = 0; q2 < 64; q2++) {
            Er[cc][q2] = pr; Ei[cc][q2] = pi;
            if (Rf[cc][q2]) { pr = Br[cc][q2]; pi = Bi[cc][q2]; }
            else {
                float nr = pr * gRr - pi * gRi + Br[cc][q2];
                pi       = pr * gRi + pi * gRr + Bi[cc][q2];
                pr = nr;
            }
        }
    }
    __syncthreads();

    // ---- pass 2: real scan + direct packed store to zinb ----
    sre = Er[c][j]; sim = Ei[c][j];
    unsigned int* zout = (unsigned int*)zinb;          // uint index = t*1024 + m*16 + c
    const int obase = m * CTX + c;
    {
        const int tbase = j * 128;
        #pragma unroll 8
        for (int i = 0; i < 64; i++) {
            if ((mw0 >> i) & 1ull) { sre = 0.f; sim = 0.f; }
            else { float tr_ = sre * gr - sim * gi; sim = sre * gi + sim * gr; sre = tr_; }
            sre += gxs[lb + i];
            unsigned int u = (unsigned int)f2bf(sre) | ((unsigned int)f2bf(sim) << 16);
            zout[((size_t)(tbase + i) << 10) + obase] = u;
        }
        #pragma unroll 8
        for (int i = 0; i < 64; i++) {
            if ((mw1 >> i) & 1ull) { sre = 0.f; sim = 0.f; }
            else { float tr_ = sre * gr - sim * gi; sim = sre * gi + sim * gr; sre = tr_; }
            sre += gxs[lb + 65 + i];
            unsigned int u = (unsigned int)f2bf(sre) | ((unsigned int)f2bf(sim) << 16);
            zout[((size_t)(tbase + 64 + i) << 10) + obase] = u;
        }
    }
    if (j == 63) {
        fstate[obase]        = sre;
        fstate[1024 + obase] = sim;
    }
}

// ---------------- GA: 256x128 tile, 8 waves, BK=32, triple-buffered depth-2 prefetch ----------
// K-loops unrolled x3 (buffer period) so buffer indices are compile-time -> all LDS
// read/stage addresses are loop-invariant base + immediate offset.
__global__ __launch_bounds__(512, 2) void gA_gemm(
        const unsigned short* __restrict__ xb,   const unsigned short* __restrict__ zinb,
        const unsigned short* __restrict__ gob,  const unsigned short* __restrict__ skb,
        const unsigned short* __restrict__ mixb,
        const float* __restrict__ go_b, const float* __restrict__ skip_b, const float* __restrict__ mix_b,
        unsigned short* __restrict__ zg, unsigned short* __restrict__ sk2)
{
    __shared__ __align__(16) unsigned short L[49152];   // 3 buffers x (A 8192 | B 4096 | C 4096)
    const int tid = threadIdx.x;
    const int b = blockIdx.x;
    const int xcd = b & 7, q = b >> 3;                  // q in [0,32)
    const int t0 = (xcd * 4 + (q >> 3)) * 256;          // 32 t-tiles of 256 (XCD-contiguous)
    const int n0 = (q & 7) * 128;                       // 8 n-tiles of 128

    const int lane = tid & 63, w = tid >> 6;            // 8 waves
    const int wm = w >> 1, wn = w & 1;                  // 4 x 2 wave grid, wave tile 64x64
    const int l31 = lane & 31, h = lane >> 5;
    const int r = tid >> 2;                             // [0,128)
    const int csw = ((tid & 3) - ((r >> 1) & 3)) & 3;   // staging chunk permutation
    const int c8 = csw * 8;
    const int srot = (l31 >> 1) & 3;                    // fragment de-swizzle rotation
    const int dst8 = tid * 8;

    f32x16 accg[2][2], acck[2][2];
    #pragma unroll
    for (int mi = 0; mi < 2; mi++)
        #pragma unroll
        for (int ni = 0; ni < 2; ni++)
            #pragma unroll
            for (int e = 0; e < 16; e++) { accg[mi][ni][e] = 0.f; acck[mi][ni][e] = 0.f; }

    // ---- fused phase: go + skip (shared A = xb), K = 1024, 32 tiles of BK=32 ----
    {
        const unsigned short* gA0 = xb  + (size_t)(t0 + r)       * IN_DIM + c8;
        const unsigned short* gA1 = xb  + (size_t)(t0 + 128 + r) * IN_DIM + c8;
        const unsigned short* gB0 = gob + (size_t)(n0 + r)       * IN_DIM + c8;
        const unsigned short* gC0 = skb + (size_t)(n0 + r)       * IN_DIM + c8;

#define STAGE_F(bufi, kof) do {                         \
        unsigned short* _b = &L[(bufi) * 16384];        \
        gl2lds16(gA0 + (kof), _b + dst8);               \
        gl2lds16(gA1 + (kof), _b + 4096 + dst8);        \
        gl2lds16(gB0 + (kof), _b + 8192 + dst8);        \
        gl2lds16(gC0 + (kof), _b + 12288 + dst8);       \
    } while (0)

#define STEP_F(T, CUR, NXT, DOST, VMC) do {             \
        const unsigned short* As = &L[(CUR) * 16384];   \
        const unsigned short* Bs = As + 8192;           \
        const unsigned short* Cs = As + 12288;          \
        _Pragma("unroll")                               \
        for (int kh = 0; kh < 2; kh++) {                \
            const int so = ((kh * 2 + h + srot) & 3) * 8; \
            bf16x8 af[2], bg[2], bk[2];                 \
            _Pragma("unroll")                           \
            for (int mi = 0; mi < 2; mi++)              \
                af[mi] = *(const bf16x8*)&As[(wm * 64 + mi * 32 + l31) * 32 + so]; \
            _Pragma("unroll")                           \
            for (int ni = 0; ni < 2; ni++) {            \
                bg[ni] = *(const bf16x8*)&Bs[(wn * 64 + ni * 32 + l31) * 32 + so]; \
                bk[ni] = *(const bf16x8*)&Cs[(wn * 64 + ni * 32 + l31) * 32 + so]; \
            }                                           \
            if (kh == 0 && (DOST)) STAGE_F(NXT, ((T) + 2) * 32); \
            __builtin_amdgcn_s_setprio(1);              \
            _Pragma("unroll")                           \
            for (int mi = 0; mi < 2; mi++)              \
                _Pragma("unroll")                       \
                for (int ni = 0; ni < 2; ni++) {        \
                    accg[mi][ni] = __builtin_amdgcn_mfma_f32_32x32x16_bf16(af[mi], bg[ni], accg[mi][ni], 0, 0, 0); \
                    acck[mi][ni] = __builtin_amdgcn_mfma_f32_32x32x16_bf16(af[mi], bk[ni], acck[mi][ni], 0, 0, 0); \
                }                                       \
            __builtin_amdgcn_s_setprio(0);              \
        }                                               \
        asm volatile("s_waitcnt vmcnt(" #VMC ")" ::: "memory"); \
        __builtin_amdgcn_s_barrier();                   \
    } while (0)

        STAGE_F(0, 0);
        STAGE_F(1, 32);
        asm volatile("s_waitcnt vmcnt(4)" ::: "memory");
        __builtin_amdgcn_s_barrier();

        for (int t3i = 0; t3i < 30; t3i += 3) {
            STEP_F(t3i,     0, 2, 1, 4);
            STEP_F(t3i + 1, 1, 0, 1, 4);
            STEP_F(t3i + 2, 2, 1, 1, 4);
        }
        STEP_F(30, 0, 2, 0, 0);
        STEP_F(31, 1, 0, 0, 0);
#undef STEP_F
#undef STAGE_F
    }

    // sigmoid (packed bf16 pairs) + sk2 write
    unsigned int sigp[32];
    #pragma unroll
    for (int mi = 0; mi < 2; mi++)
        #pragma unroll
        for (int ni = 0; ni < 2; ni++) {
            int n = n0 + wn * 64 + ni * 32 + l31;
            float gb = go_b[n];
            float sb_ = skip_b[n];
            #pragma unroll
            for (int reg = 0; reg < 16; reg++) {
                int row = (reg & 3) + 8 * (reg >> 2) + 4 * h;
                int t = t0 + wm * 64 + mi * 32 + row;
                float s = 1.f / (1.f + expf(-(accg[mi][ni][reg] + gb)));
                sk2[(size_t)t * OUT_DIM + n] = f2bf((acck[mi][ni][reg] + sb_) * (1.f - s));
                unsigned int pk = (unsigned int)f2bf(s);
                int idx = (mi * 2 + ni) * 8 + (reg >> 1);
                if (reg & 1) sigp[idx] |= pk << 16;
                else         sigp[idx]  = pk;
            }
        }

    // ---- mix phase, K = 2048, 64 tiles of BK=32 ----
    #pragma unroll
    for (int mi = 0; mi < 2; mi++)
        #pragma unroll
        for (int ni = 0; ni < 2; ni++)
            #pragma unroll
            for (int e = 0; e < 16; e++) accg[mi][ni][e] = 0.f;
    {
        const unsigned short* mA0 = zinb + (size_t)(t0 + r)       * KMIX + c8;
        const unsigned short* mA1 = zinb + (size_t)(t0 + 128 + r) * KMIX + c8;
        const unsigned short* mB0 = mixb + (size_t)(n0 + r)       * KMIX + c8;

#define STAGE_M(bufi, kof) do {                         \
        unsigned short* _b = &L[(bufi) * 16384];        \
        gl2lds16(mA0 + (kof), _b + dst8);               \
        gl2lds16(mA1 + (kof), _b + 4096 + dst8);        \
        gl2lds16(mB0 + (kof), _b + 8192 + dst8);        \
    } while (0)

#define STEP_M(T, CUR, NXT, DOST, VMC) do {             \
        const unsigned short* As = &L[(CUR) * 16384];   \
        const unsigned short* Bs = As + 8192;           \
        _Pragma("unroll")                               \
        for (int kh = 0; kh < 2; kh++) {                \
            const int so = ((kh * 2 + h + srot) & 3) * 8; \
            bf16x8 af[2], bf[2];                        \
            _Pragma("unroll")                           \
            for (int mi = 0; mi < 2; mi++)              \
                af[mi] = *(const bf16x8*)&As[(wm * 64 + mi * 32 + l31) * 32 + so]; \
            _Pragma("unroll")                           \
            for (int ni = 0; ni < 2; ni++)              \
                bf[ni] = *(const bf16x8*)&Bs[(wn * 64 + ni * 32 + l31) * 32 + so]; \
            if (kh == 0 && (DOST)) STAGE_M(NXT, ((T) + 2) * 32); \
            __builtin_amdgcn_s_setprio(1);              \
            _Pragma("unroll")                           \
            for (int mi = 0; mi < 2; mi++)              \
                _Pragma("unroll")                       \
                for (int ni = 0; ni < 2; ni++)          \
                    accg[mi][ni] = __builtin_amdgcn_mfma_f32_32x32x16_bf16(af[mi], bf[ni], accg[mi][ni], 0, 0, 0); \
            __builtin_amdgcn_s_setprio(0);              \
        }                                               \
        asm volatile("s_waitcnt vmcnt(" #VMC ")" ::: "memory"); \
        __builtin_amdgcn_s_barrier();                   \
    } while (0)

        STAGE_M(0, 0);
        STAGE_M(1, 32);
        asm volatile("s_waitcnt vmcnt(3)" ::: "memory");
        __builtin_amdgcn_s_barrier();

        for (int t3i = 0; t3i < 60; t3i += 3) {
            STEP_M(t3i,     0, 2, 1, 3);
            STEP_M(t3i + 1, 1, 0, 1, 3);
            STEP_M(t3i + 2, 2, 1, 1, 3);
        }
        STEP_M(60, 0, 2, 1, 3);
        STEP_M(61, 1, 0, 1, 3);
        STEP_M(62, 2, 1, 0, 0);
        STEP_M(63, 0, 2, 0, 0);
#undef STEP_M
#undef STAGE_M
    }

    #pragma unroll
    for (int mi = 0; mi < 2; mi++)
        #pragma unroll
        for (int ni = 0; ni < 2; ni++) {
            int n = n0 + wn * 64 + ni * 32 + l31;
            float mb_ = mix_b[n];
            #pragma unroll
            for (int reg = 0; reg < 16; reg++) {
                int row = (reg & 3) + 8 * (reg >> 2) + 4 * h;
                int t = t0 + wm * 64 + mi * 32 + row;
                unsigned int u = sigp[(mi * 2 + ni) * 8 + (reg >> 1)];
                float sig = bf2f((unsigned short)((reg & 1) ? (u >> 16) : (u & 0xffff)));
                zg[(size_t)t * OUT_DIM + n] = f2bf((accg[mi][ni][reg] + mb_) * sig);
            }
        }
}

// ---------------- G3: LayerNorm + residual (bf16 in, fp32 out) + final_state copy ------------
__global__ __launch_bounds__(256) void g3_ln(const unsigned short* __restrict__ zg,
        const unsigned short* __restrict__ sk2, const float* __restrict__ fstate,
        float* __restrict__ out, int out_size)
{
    __shared__ float sb[4], qb[4];
    __shared__ float mu_s, rstd_s;
    const int t = blockIdx.x;
    const int tid = threadIdx.x;
    ushort4 zu = *(const ushort4*)&zg [(size_t)t * OUT_DIM + tid * 4];
    ushort4 su = *(const ushort4*)&sk2[(size_t)t * OUT_DIM + tid * 4];
    float z0 = bf2f(zu.x), z1 = bf2f(zu.y), z2 = bf2f(zu.z), z3 = bf2f(zu.w);
    float s0 = bf2f(su.x), s1 = bf2f(su.y), s2 = bf2f(su.z), s3 = bf2f(su.w);
    float s = z0 + z1 + z2 + z3;
    float q = z0*z0 + z1*z1 + z2*z2 + z3*z3;
    #pragma unroll
    for (int off = 32; off > 0; off >>= 1) {
        s += __shfl_down(s, off, 64);
        q += __shfl_down(q, off, 64);
    }
    int wid = tid >> 6;
    if ((tid & 63) == 0) { sb[wid] = s; qb[wid] = q; }
    __syncthreads();
    if (tid == 0) {
        float S = sb[0] + sb[1] + sb[2] + sb[3];
        float Q = qb[0] + qb[1] + qb[2] + qb[3];
        float mu = S * (1.f / 1024.f);
        float var = Q * (1.f / 1024.f) - mu * mu;
        mu_s = mu; rstd_s = rsqrtf(var + 1e-5f);
    }
    __syncthreads();
    float mu = mu_s, rs = rstd_s;
    float4 o;
    o.x = (z0 - mu) * rs + s0;
    o.y = (z1 - mu) * rs + s1;
    o.z = (z2 - mu) * rs + s2;
    o.w = (z3 - mu) * rs + s3;
    *(float4*)&out[(size_t)t * OUT_DIM + tid * 4] = o;

    if (t < 8) {   // folded g4: final_state copy
        int i = t * 256 + tid;
        long long base = (long long)T_DIM * OUT_DIM;
        if (base + i < (long long)out_size) out[base + i] = fstate[i];
    }
}

extern "C" void kernel_launch(void* const* d_in, const int* in_sizes, int n_in,
                              void* d_out, int out_size, void* d_ws, size_t ws_size,
                              hipStream_t stream) {
    const float* x        = (const float*)d_in[0];
    const float* state_re = (const float*)d_in[1];
    const float* state_im = (const float*)d_in[2];
    const void*  startp   = d_in[3];
    const float* pre_w    = (const float*)d_in[5];
    const float* pre_b    = (const float*)d_in[6];
    const float* gi_w     = (const float*)d_in[7];
    const float* gi_b     = (const float*)d_in[8];
    const float* go_w     = (const float*)d_in[9];
    const float* go_b     = (const float*)d_in[10];
    const float* skip_w   = (const float*)d_in[11];
    const float* skip_b   = (const float*)d_in[12];
    const float* mix_w    = (const float*)d_in[13];
    const float* mix_b    = (const float*)d_in[14];
    const float* ffa_a    = (const float*)d_in[15];
    const float* ffa_b    = (const float*)d_in[16];

    float* ws = (float*)d_ws;
    float*          gxT    = ws;
    unsigned short* zinb   = (unsigned short*)(ws + 8912896);
    unsigned short* xb     = (unsigned short*)(ws + 17301504);
    unsigned short* gob    = (unsigned short*)(ws + 21495808);
    unsigned short* skb    = (unsigned short*)(ws + 22020096);
    unsigned short* mixb   = (unsigned short*)(ws + 22544384);
    unsigned short* zg     = (unsigned short*)(ws + 23592960);
    unsigned short* sk2    = (unsigned short*)(ws + 27787264);
    float*          fstate = ws + 31981568;
    unsigned char*  mask   = (unsigned char*)(ws + 31983616);
    unsigned long long* mask64 = (unsigned long long*)(ws + 31985664);
    unsigned short* pwb    = zg;            // borrow zg region pre-gA
    unsigned short* gwb    = zg + 65536;
    float* out = (float*)d_out;

    hipLaunchKernelGGL(c0_conv,  dim3(1536), dim3(256),  0, stream, x, go_w, skip_w, mix_w, pre_w, gi_w,
                                                          startp, xb, gob, skb, mixb, pwb, gwb, mask, mask64);
    hipLaunchKernelGGL(k1_mfma,  dim3(256),  dim3(256),  0, stream, xb, pwb, gwb, pre_b, gi_b, gxT);
    hipLaunchKernelGGL(k2_scan,  dim3(64),   dim3(1024), 0, stream, gxT, mask64, state_re, state_im, ffa_a, ffa_b, zinb, fstate);
    hipLaunchKernelGGL(gA_gemm,  dim3(256),  dim3(512),  0, stream, xb, zinb, gob, skb, mixb, go_b, skip_b, mix_b, zg, sk2);
    hipLaunchKernelGGL(g3_ln,    dim3(8192), dim3(256),  0, stream, zg, sk2, fstate, out, out_size);
}

// Round 6
// 257.049 us; speedup vs baseline: 1.2600x; 1.0246x over previous
//
#include <hip/hip_runtime.h>
#include <math.h>

#define T_DIM 8192
#define IN_DIM 1024
#define TRACE 64
#define CTX 16
#define OUT_DIM 1024
#define KMIX 2048

typedef __attribute__((ext_vector_type(8))) short bf16x8;
typedef __attribute__((ext_vector_type(4))) float f32x4;
typedef __attribute__((ext_vector_type(16))) float f32x16;

__device__ __forceinline__ unsigned short f2bf(float f) {
    unsigned int u = __float_as_uint(f);
    u = (u + 0x7FFFu + ((u >> 16) & 1u)) >> 16;
    return (unsigned short)u;
}
__device__ __forceinline__ float bf2f(unsigned short b) {
    return __uint_as_float(((unsigned int)b) << 16);
}

__device__ __forceinline__ void gl2lds16(const void* g, void* l) {
    __builtin_amdgcn_global_load_lds(
        (const __attribute__((address_space(1))) unsigned int*)g,
        (__attribute__((address_space(3))) unsigned int*)l,
        16, 0, 0);
}

// ---------------- ws layout (float offsets) ----------------
// gxT   fp32 [64][8192]      @ 0         (524288 f)
// zinb  bf16 [8192][2048]    @ 8912896   (8388608 f)   k-order: k' = m*32 + 2c + (0 re/1 im)
// xb    bf16 [8192][1024]    @ 17301504  (4194304 f)
// gob   bf16 [1024][1024]    @ 21495808  (524288 f)
// skb   bf16 [1024][1024]    @ 22020096  (524288 f)
// mixb  bf16 [1024][2048]    @ 22544384  (1048576 f)   same permuted k-order as zinb
// zg    bf16 [8192][1024]    @ 23592960  (4194304 f)   [pwb/gwb borrow pre-gA]
// sk2   bf16 [8192][1024]    @ 27787264  (4194304 f)
// fstate fp32 [2048]         @ 31981568
// mask  u8   [8192]          @ 31983616  (2048 f)
// mask64 u64 [128]           @ 31985664  (256 f)

// ---------------- C0: fp32 -> bf16 conversions + start-mask normalize + bit-pack -------------
__global__ __launch_bounds__(256) void c0_conv(const float* __restrict__ x,
        const float* __restrict__ gw, const float* __restrict__ sw, const float* __restrict__ mw,
        const float* __restrict__ pw, const float* __restrict__ giw,
        const void* __restrict__ startp,
        unsigned short* __restrict__ xb, unsigned short* __restrict__ gob,
        unsigned short* __restrict__ skb, unsigned short* __restrict__ mixb,
        unsigned short* __restrict__ pwb, unsigned short* __restrict__ gwb,
        unsigned char* __restrict__ mask, unsigned long long* __restrict__ mask64)
{
    if (blockIdx.x == 0) {
        __shared__ int nonbool;
        int tid = threadIdx.x;
        if (tid == 0) nonbool = 0;
        __syncthreads();
        const unsigned int* wv = (const unsigned int*)startp;
        #pragma unroll
        for (int p = 0; p < 8; p++) {
            unsigned int a = wv[tid * 8 + p];
            if (a > 1u) nonbool = 1;
        }
        __syncthreads();
        if (nonbool) {
            const unsigned char* s8 = (const unsigned char*)startp;
            for (int i = tid; i < T_DIM; i += 256) mask[i] = (unsigned char)(s8[i] != 0);
        } else {
            const int* s32 = (const int*)startp;
            for (int i = tid; i < T_DIM; i += 256) mask[i] = (unsigned char)(s32[i] != 0);
        }
        __syncthreads();   // mask bytes visible block-wide; pack 64 bits/thread
        if (tid < 128) {
            unsigned long long wv2 = 0ull;
            int base = tid * 64;
            #pragma unroll 8
            for (int b2 = 0; b2 < 64; b2++)
                wv2 |= ((unsigned long long)(mask[base + b2] & 1)) << b2;
            mask64[tid] = wv2;
        }
    }
    // part A: straight conversions (x, go_w, skip_w, pre_w, gi_w)
    const size_t QX = 2097152, QG = 262144, QS = 262144, QP = 16384, QI = 16384;
    const size_t totalA = QX + QG + QS + QP + QI;   // 2654208
    for (size_t q = (size_t)blockIdx.x * blockDim.x + threadIdx.x; q < totalA;
         q += (size_t)gridDim.x * blockDim.x) {
        const float* src; unsigned short* dst; size_t i;
        if (q < QX)               { src = x;   dst = xb;   i = q; }
        else if (q < QX+QG)       { src = gw;  dst = gob;  i = q - QX; }
        else if (q < QX+QG+QS)    { src = sw;  dst = skb;  i = q - QX - QG; }
        else if (q < QX+QG+QS+QP) { src = pw;  dst = pwb;  i = q - QX - QG - QS; }
        else                      { src = giw; dst = gwb;  i = q - QX - QG - QS - QP; }
        float4 v = *(const float4*)(src + i * 4);
        ushort4 o;
        o.x = f2bf(v.x); o.y = f2bf(v.y); o.z = f2bf(v.z); o.w = f2bf(v.w);
        *(ushort4*)(dst + i * 4) = o;
    }
    // part B: mix_w with k-permutation: k = mm*32 + p*16 + cc -> k' = mm*32 + 2*cc + p
    const size_t QM = 524288;
    for (size_t q = (size_t)blockIdx.x * blockDim.x + threadIdx.x; q < QM;
         q += (size_t)gridDim.x * blockDim.x) {
        float4 v = *(const float4*)(mw + q * 4);
        int flat = (int)(q * 4);
        int n  = flat >> 11;
        int kk = flat & 2047;
        int mm = kk >> 5;
        int w_ = kk & 31;
        int p  = w_ >> 4;
        int cc = w_ & 15;            // multiple of 4 (flat is x4)
        int kb = (n << 11) + mm * 32 + (cc << 1) + p;
        mixb[kb]     = f2bf(v.x);
        mixb[kb + 2] = f2bf(v.y);
        mixb[kb + 4] = f2bf(v.z);
        mixb[kb + 6] = f2bf(v.w);
    }
}

// ---------------- K1: MFMA gated_x, 256 blocks of 32t x 128m, swizzled LDS --------------------
__global__ __launch_bounds__(256) void k1_mfma(const unsigned short* __restrict__ xb,
        const unsigned short* __restrict__ pwb, const unsigned short* __restrict__ gwb,
        const float* __restrict__ pre_b, const float* __restrict__ gi_b,
        float* __restrict__ gxT)
{
    __shared__ __align__(16) unsigned short As[1024];
    __shared__ __align__(16) unsigned short Bs[4096];
    __shared__ float sgE[64][33];

    const int tid = threadIdx.x;
    const int t0 = blockIdx.x * 32;
    const int lane = tid & 63, w = tid >> 6;
    const int quad = lane >> 4, l16 = lane & 15;
    const int r = tid >> 2, s4 = tid & 3;
    const int csw = (s4 - ((r >> 1) & 3)) & 3;

    f32x4 acc[2][2];
    const f32x4 zero4 = {0.f, 0.f, 0.f, 0.f};
    #pragma unroll
    for (int mi = 0; mi < 2; mi++)
        #pragma unroll
        for (int ni = 0; ni < 2; ni++) acc[mi][ni] = zero4;

    const int sfr = (quad + ((l16 >> 1) & 3)) & 3;

    for (int k0 = 0; k0 < IN_DIM; k0 += 32) {
        __syncthreads();
        if (tid < 128) {
            int ra = tid >> 2;
            int ca = ((tid & 3) - ((ra >> 1) & 3)) & 3;
            gl2lds16(xb + (size_t)(t0 + ra) * IN_DIM + k0 + ca * 8, As + tid * 8);
        }
        gl2lds16(pwb + (size_t)r * IN_DIM + k0 + csw * 8, Bs + tid * 8);
        gl2lds16(gwb + (size_t)r * IN_DIM + k0 + csw * 8, Bs + 2048 + tid * 8);
        asm volatile("s_waitcnt vmcnt(0)" ::: "memory");
        __syncthreads();
        bf16x8 af[2], bf[2];
        #pragma unroll
        for (int mi = 0; mi < 2; mi++)
            af[mi] = *(const bf16x8*)&As[(mi * 16 + l16) * 32 + sfr * 8];
        #pragma unroll
        for (int ni = 0; ni < 2; ni++)
            bf[ni] = *(const bf16x8*)&Bs[(w * 32 + ni * 16 + l16) * 32 + sfr * 8];
        #pragma unroll
        for (int mi = 0; mi < 2; mi++)
            #pragma unroll
            for (int ni = 0; ni < 2; ni++)
                acc[mi][ni] = __builtin_amdgcn_mfma_f32_16x16x32_bf16(af[mi], bf[ni], acc[mi][ni], 0, 0, 0);
    }

    if (w >= 2) {
        #pragma unroll
        for (int mi = 0; mi < 2; mi++)
            #pragma unroll
            for (int ni = 0; ni < 2; ni++) {
                int mg = (w - 2) * 32 + ni * 16 + l16;
                float gb = gi_b[mg];
                #pragma unroll
                for (int rr = 0; rr < 4; rr++) {
                    int tl = mi * 16 + quad * 4 + rr;
                    sgE[mg][tl] = 1.f / (1.f + expf(-(acc[mi][ni][rr] + gb)));
                }
            }
    }
    __syncthreads();
    if (w < 2) {
        #pragma unroll
        for (int mi = 0; mi < 2; mi++)
            #pragma unroll
            for (int ni = 0; ni < 2; ni++) {
                int mp = w * 32 + ni * 16 + l16;
                float pb = pre_b[mp];
                float4 o;
                float* po = &o.x;
                #pragma unroll
                for (int rr = 0; rr < 4; rr++) {
                    int tl = mi * 16 + quad * 4 + rr;
                    po[rr] = (acc[mi][ni][rr] + pb) * sgE[mp][tl];
                }
                *(float4*)&gxT[(size_t)mp * T_DIM + t0 + mi * 16 + quad * 4] = o;
            }
    }
}

// ---------------- K2: resettable complex scan, FULL-CHIP, direct zinb[t][k'] output -----------
// Round-6: r5's k2 used 64 blocks = 1/4 chip while writing 32 MB (>=20 us of write time alone).
// Now grid 256 = (m, quarter): every block redundantly runs the cheap pass-1 (full-row 128-t
// chunk summaries from zero) + the 64-step serial scan, then pass-2 writes only its 2048-t
// quarter with ALL 1024 threads (32 t per thread). Carry-in at a 32-t sub-boundary is rebuilt
// from the 128-t boundary state via the affine identity state_k(E) = B_k + A_k*E, where
// A_k = gamma^k (no reset in chunk prefix) or 0 (reset) -- same algebra the 128-level scan uses.
__global__ __launch_bounds__(1024, 1) void k2_scan(const float* __restrict__ gxT,
        const unsigned long long* __restrict__ mask64,
        const float* __restrict__ state_re, const float* __restrict__ state_im,
        const float* __restrict__ ffa_a, const float* __restrict__ ffa_b,
        unsigned short* __restrict__ zinb, float* __restrict__ fstate)
{
    const int m  = blockIdx.x >> 2;
    const int qd = blockIdx.x & 3;             // quarter: t in [qd*2048, qd*2048+2048)
    const int tid = threadIdx.x;
    const int c = tid & 15, j = tid >> 4;      // j in [0,64): pass-1 chunk of 128 t
    __shared__ __align__(16) float gxs[8192 + 128];   // padded: idx = t + (t>>6)
    __shared__ float Br[16][65], Bi[16][65], Er[16][65], Ei[16][65];
    __shared__ unsigned char Rf[16][65];
    __shared__ float B32r[16][16][3], B32i[16][16][3];   // from-zero states after 32/64/96 t
    __shared__ unsigned char sRf[16][16][3];             // reset-in-prefix flags

    const float am = -fabsf(ffa_a[m]);
    const float bc = ffa_b[c];
    const float er = expf(am);
    const float gr = er * cosf(bc);
    const float gi = er * sinf(bc);

    // ---- coalesced one-time stage of the gxT row ----
    {
        const float4* gx4 = (const float4*)(gxT + (size_t)m * T_DIM);
        #pragma unroll
        for (int it = 0; it < 2; it++) {
            int g = it * 1024 + tid;
            float4 v = gx4[g];
            int t = g * 4;
            gxs[t     + ( t      >> 6)] = v.x;
            gxs[t + 1 + ((t + 1) >> 6)] = v.y;
            gxs[t + 2 + ((t + 2) >> 6)] = v.z;
            gxs[t + 3 + ((t + 3) >> 6)] = v.w;
        }
    }
    const unsigned long long mw0 = mask64[j * 2];
    const unsigned long long mw1 = mask64[j * 2 + 1];
    __syncthreads();

    const int lb = j * 130;                 // padded base of this thread's 128-t chunk
    const int gloc = j - qd * 16;           // own-quarter chunk index (valid if 0..15)
    const bool own = (unsigned)gloc < 16u;

    // ---- pass 1: chunk summary from zero, capturing sub-states at 32/64/96 ----
    float sre = 0.f, sim = 0.f;
    #pragma unroll 8
    for (int i = 0; i < 32; i++) {
        if ((mw0 >> i) & 1ull) { sre = 0.f; sim = 0.f; }
        else { float tr_ = sre * gr - sim * gi; sim = sre * gi + sim * gr; sre = tr_; }
        sre += gxs[lb + i];
    }
    if (own) { B32r[c][gloc][0] = sre; B32i[c][gloc][0] = sim;
               sRf[c][gloc][0] = ((mw0 & 0xffffffffull) != 0ull) ? 1 : 0; }
    #pragma unroll 8
    for (int i = 0; i < 32; i++) {
        if ((mw0 >> (i + 32)) & 1ull) { sre = 0.f; sim = 0.f; }
        else { float tr_ = sre * gr - sim * gi; sim = sre * gi + sim * gr; sre = tr_; }
        sre += gxs[lb + 32 + i];
    }
    if (own) { B32r[c][gloc][1] = sre; B32i[c][gloc][1] = sim;
               sRf[c][gloc][1] = (mw0 != 0ull) ? 1 : 0; }
    #pragma unroll 8
    for (int i = 0; i < 32; i++) {
        if ((mw1 >> i) & 1ull) { sre = 0.f; sim = 0.f; }
        else { float tr_ = sre * gr - sim * gi; sim = sre * gi + sim * gr; sre = tr_; }
        sre += gxs[lb + 65 + i];
    }
    if (own) { B32r[c][gloc][2] = sre; B32i[c][gloc][2] = sim;
               sRf[c][gloc][2] = ((mw0 != 0ull) || ((mw1 & 0xffffffffull) != 0ull)) ? 1 : 0; }
    #pragma unroll 8
    for (int i = 0; i < 32; i++) {
        if ((mw1 >> (i + 32)) & 1ull) { sre = 0.f; sim = 0.f; }
        else { float tr_ = sre * gr - sim * gi; sim = sre * gi + sim * gr; sre = tr_; }
        sre += gxs[lb + 97 + i];
    }
    Br[c][j] = sre; Bi[c][j] = sim; Rf[c][j] = ((mw0 | mw1) != 0ull) ? 1 : 0;
    __syncthreads();

    // ---- serial summary scan: 16 threads, one per c (unchanged) ----
    if (tid < 16) {
        const int cc = tid;
        float b2 = 128.f * ffa_b[cc];
        float e128 = expf(128.f * am);
        float gRr = e128 * cosf(b2);
        float gRi = e128 * sinf(b2);
        float pr = state_re[m * CTX + cc], pi = state_im[m * CTX + cc];
        for (int q2 = 0; q2 < 64; q2++) {
            Er[cc][q2] = pr; Ei[cc][q2] = pi;
            if (Rf[cc][q2]) { pr = Br[cc][q2]; pi = Bi[cc][q2]; }
            else {
                float nr = pr * gRr - pi * gRi + Br[cc][q2];
                pi       = pr * gRi + pi * gRr + Bi[cc][q2];
                pr = nr;
            }
        }
    }
    __syncthreads();

    // ---- pass 2: this quarter only, 32 t per thread, direct packed store to zinb ----
    {
        const int gl2 = j >> 2, s = j & 3;       // chunk-in-quarter, 32-t sub-chunk
        const int g = qd * 16 + gl2;             // global 128-t chunk
        const unsigned long long w0 = mask64[g * 2];
        const unsigned long long w1 = mask64[g * 2 + 1];
        const unsigned int mbits = (unsigned int)(((s < 2) ? w0 : w1) >> ((s & 1) * 32));
        float str, sti;
        {
            float E_r = Er[c][g], E_i = Ei[c][g];
            if (s == 0) { str = E_r; sti = E_i; }
            else if (sRf[c][gl2][s - 1]) { str = B32r[c][gl2][s - 1]; sti = B32i[c][gl2][s - 1]; }
            else {
                float ang = 32.f * (float)s * bc;
                float mag = expf(32.f * (float)s * am);
                float gsr = mag * cosf(ang), gsi = mag * sinf(ang);
                str = B32r[c][gl2][s - 1] + E_r * gsr - E_i * gsi;
                sti = B32i[c][gl2][s - 1] + E_r * gsi + E_i * gsr;
            }
        }
        const int pb = g * 130 + (s >> 1) * 65 + (s & 1) * 32;   // padded gxs base
        const int tstart = g * 128 + s * 32;
        unsigned int* zout = (unsigned int*)zinb;   // uint index = t*1024 + m*16 + c
        const int obase = m * CTX + c;
        #pragma unroll 8
        for (int i = 0; i < 32; i++) {
            if ((mbits >> i) & 1u) { str = 0.f; sti = 0.f; }
            else { float tr_ = str * gr - sti * gi; sti = str * gi + sti * gr; str = tr_; }
            str += gxs[pb + i];
            unsigned int u = (unsigned int)f2bf(str) | ((unsigned int)f2bf(sti) << 16);
            zout[((size_t)(tstart + i) << 10) + obase] = u;
        }
        if (qd == 3 && j == 63) {
            fstate[obase]        = str;
            fstate[1024 + obase] = sti;
        }
    }
}

// ---------------- GA: 256x128 tile, 8 waves, BK=32, triple-buffered depth-2 prefetch ----------
__global__ __launch_bounds__(512, 2) void gA_gemm(
        const unsigned short* __restrict__ xb,   const unsigned short* __restrict__ zinb,
        const unsigned short* __restrict__ gob,  const unsigned short* __restrict__ skb,
        const unsigned short* __restrict__ mixb,
        const float* __restrict__ go_b, const float* __restrict__ skip_b, const float* __restrict__ mix_b,
        unsigned short* __restrict__ zg, unsigned short* __restrict__ sk2)
{
    __shared__ __align__(16) unsigned short L[49152];   // 3 buffers x (A 8192 | B 4096 | C 4096)
    const int tid = threadIdx.x;
    const int b = blockIdx.x;
    const int xcd = b & 7, q = b >> 3;                  // q in [0,32)
    const int t0 = (xcd * 4 + (q >> 3)) * 256;          // 32 t-tiles of 256 (XCD-contiguous)
    const int n0 = (q & 7) * 128;                       // 8 n-tiles of 128

    const int lane = tid & 63, w = tid >> 6;            // 8 waves
    const int wm = w >> 1, wn = w & 1;                  // 4 x 2 wave grid, wave tile 64x64
    const int l31 = lane & 31, h = lane >> 5;
    const int r = tid >> 2;                             // [0,128)
    const int csw = ((tid & 3) - ((r >> 1) & 3)) & 3;   // staging chunk permutation
    const int c8 = csw * 8;
    const int srot = (l31 >> 1) & 3;                    // fragment de-swizzle rotation
    const int dst8 = tid * 8;

    f32x16 accg[2][2], acck[2][2];
    #pragma unroll
    for (int mi = 0; mi < 2; mi++)
        #pragma unroll
        for (int ni = 0; ni < 2; ni++)
            #pragma unroll
            for (int e = 0; e < 16; e++) { accg[mi][ni][e] = 0.f; acck[mi][ni][e] = 0.f; }

    // ---- fused phase: go + skip (shared A = xb), K = 1024, 32 tiles of BK=32 ----
    {
        const unsigned short* gA0 = xb  + (size_t)(t0 + r)       * IN_DIM + c8;
        const unsigned short* gA1 = xb  + (size_t)(t0 + 128 + r) * IN_DIM + c8;
        const unsigned short* gB0 = gob + (size_t)(n0 + r)       * IN_DIM + c8;
        const unsigned short* gC0 = skb + (size_t)(n0 + r)       * IN_DIM + c8;

#define STAGE_F(bufi, kof) do {                         \
        unsigned short* _b = &L[(bufi) * 16384];        \
        gl2lds16(gA0 + (kof), _b + dst8);               \
        gl2lds16(gA1 + (kof), _b + 4096 + dst8);        \
        gl2lds16(gB0 + (kof), _b + 8192 + dst8);        \
        gl2lds16(gC0 + (kof), _b + 12288 + dst8);       \
    } while (0)

#define STEP_F(T, CUR, NXT, DOST, VMC) do {             \
        const unsigned short* As = &L[(CUR) * 16384];   \
        const unsigned short* Bs = As + 8192;           \
        const unsigned short* Cs = As + 12288;          \
        _Pragma("unroll")                               \
        for (int kh = 0; kh < 2; kh++) {                \
            const int so = ((kh * 2 + h + srot) & 3) * 8; \
            bf16x8 af[2], bg[2], bk[2];                 \
            _Pragma("unroll")                           \
            for (int mi = 0; mi < 2; mi++)              \
                af[mi] = *(const bf16x8*)&As[(wm * 64 + mi * 32 + l31) * 32 + so]; \
            _Pragma("unroll")                           \
            for (int ni = 0; ni < 2; ni++) {            \
                bg[ni] = *(const bf16x8*)&Bs[(wn * 64 + ni * 32 + l31) * 32 + so]; \
                bk[ni] = *(const bf16x8*)&Cs[(wn * 64 + ni * 32 + l31) * 32 + so]; \
            }                                           \
            if (kh == 0 && (DOST)) STAGE_F(NXT, ((T) + 2) * 32); \
            __builtin_amdgcn_s_setprio(1);              \
            _Pragma("unroll")                           \
            for (int mi = 0; mi < 2; mi++)              \
                _Pragma("unroll")                       \
                for (int ni = 0; ni < 2; ni++) {        \
                    accg[mi][ni] = __builtin_amdgcn_mfma_f32_32x32x16_bf16(af[mi], bg[ni], accg[mi][ni], 0, 0, 0); \
                    acck[mi][ni] = __builtin_amdgcn_mfma_f32_32x32x16_bf16(af[mi], bk[ni], acck[mi][ni], 0, 0, 0); \
                }                                       \
            __builtin_amdgcn_s_setprio(0);              \
        }                                               \
        asm volatile("s_waitcnt vmcnt(" #VMC ")" ::: "memory"); \
        __builtin_amdgcn_s_barrier();                   \
    } while (0)

        STAGE_F(0, 0);
        STAGE_F(1, 32);
        asm volatile("s_waitcnt vmcnt(4)" ::: "memory");
        __builtin_amdgcn_s_barrier();

        for (int t3i = 0; t3i < 30; t3i += 3) {
            STEP_F(t3i,     0, 2, 1, 4);
            STEP_F(t3i + 1, 1, 0, 1, 4);
            STEP_F(t3i + 2, 2, 1, 1, 4);
        }
        STEP_F(30, 0, 2, 0, 0);
        STEP_F(31, 1, 0, 0, 0);
#undef STEP_F
#undef STAGE_F
    }

    // sigmoid (packed bf16 pairs) + sk2 write
    unsigned int sigp[32];
    #pragma unroll
    for (int mi = 0; mi < 2; mi++)
        #pragma unroll
        for (int ni = 0; ni < 2; ni++) {
            int n = n0 + wn * 64 + ni * 32 + l31;
            float gb = go_b[n];
            float sb_ = skip_b[n];
            #pragma unroll
            for (int reg = 0; reg < 16; reg++) {
                int row = (reg & 3) + 8 * (reg >> 2) + 4 * h;
                int t = t0 + wm * 64 + mi * 32 + row;
                float s = 1.f / (1.f + expf(-(accg[mi][ni][reg] + gb)));
                sk2[(size_t)t * OUT_DIM + n] = f2bf((acck[mi][ni][reg] + sb_) * (1.f - s));
                unsigned int pk = (unsigned int)f2bf(s);
                int idx = (mi * 2 + ni) * 8 + (reg >> 1);
                if (reg & 1) sigp[idx] |= pk << 16;
                else         sigp[idx]  = pk;
            }
        }

    // ---- mix phase, K = 2048, 64 tiles of BK=32 ----
    #pragma unroll
    for (int mi = 0; mi < 2; mi++)
        #pragma unroll
        for (int ni = 0; ni < 2; ni++)
            #pragma unroll
            for (int e = 0; e < 16; e++) accg[mi][ni][e] = 0.f;
    {
        const unsigned short* mA0 = zinb + (size_t)(t0 + r)       * KMIX + c8;
        const unsigned short* mA1 = zinb + (size_t)(t0 + 128 + r) * KMIX + c8;
        const unsigned short* mB0 = mixb + (size_t)(n0 + r)       * KMIX + c8;

#define STAGE_M(bufi, kof) do {                         \
        unsigned short* _b = &L[(bufi) * 16384];        \
        gl2lds16(mA0 + (kof), _b + dst8);               \
        gl2lds16(mA1 + (kof), _b + 4096 + dst8);        \
        gl2lds16(mB0 + (kof), _b + 8192 + dst8);        \
    } while (0)

#define STEP_M(T, CUR, NXT, DOST, VMC) do {             \
        const unsigned short* As = &L[(CUR) * 16384];   \
        const unsigned short* Bs = As + 8192;           \
        _Pragma("unroll")                               \
        for (int kh = 0; kh < 2; kh++) {                \
            const int so = ((kh * 2 + h + srot) & 3) * 8; \
            bf16x8 af[2], bf[2];                        \
            _Pragma("unroll")                           \
            for (int mi = 0; mi < 2; mi++)              \
                af[mi] = *(const bf16x8*)&As[(wm * 64 + mi * 32 + l31) * 32 + so]; \
            _Pragma("unroll")                           \
            for (int ni = 0; ni < 2; ni++)              \
                bf[ni] = *(const bf16x8*)&Bs[(wn * 64 + ni * 32 + l31) * 32 + so]; \
            if (kh == 0 && (DOST)) STAGE_M(NXT, ((T) + 2) * 32); \
            __builtin_amdgcn_s_setprio(1);              \
            _Pragma("unroll")                           \
            for (int mi = 0; mi < 2; mi++)              \
                _Pragma("unroll")                       \
                for (int ni = 0; ni < 2; ni++)          \
                    accg[mi][ni] = __builtin_amdgcn_mfma_f32_32x32x16_bf16(af[mi], bf[ni], accg[mi][ni], 0, 0, 0); \
            __builtin_amdgcn_s_setprio(0);              \
        }                                               \
        asm volatile("s_waitcnt vmcnt(" #VMC ")" ::: "memory"); \
        __builtin_amdgcn_s_barrier();                   \
    } while (0)

        STAGE_M(0, 0);
        STAGE_M(1, 32);
        asm volatile("s_waitcnt vmcnt(3)" ::: "memory");
        __builtin_amdgcn_s_barrier();

        for (int t3i = 0; t3i < 60; t3i += 3) {
            STEP_M(t3i,     0, 2, 1, 3);
            STEP_M(t3i + 1, 1, 0, 1, 3);
            STEP_M(t3i + 2, 2, 1, 1, 3);
        }
        STEP_M(60, 0, 2, 1, 3);
        STEP_M(61, 1, 0, 1, 3);
        STEP_M(62, 2, 1, 0, 0);
        STEP_M(63, 0, 2, 0, 0);
#undef STEP_M
#undef STAGE_M
    }

    #pragma unroll
    for (int mi = 0; mi < 2; mi++)
        #pragma unroll
        for (int ni = 0; ni < 2; ni++) {
            int n = n0 + wn * 64 + ni * 32 + l31;
            float mb_ = mix_b[n];
            #pragma unroll
            for (int reg = 0; reg < 16; reg++) {
                int row = (reg & 3) + 8 * (reg >> 2) + 4 * h;
                int t = t0 + wm * 64 + mi * 32 + row;
                unsigned int u = sigp[(mi * 2 + ni) * 8 + (reg >> 1)];
                float sig = bf2f((unsigned short)((reg & 1) ? (u >> 16) : (u & 0xffff)));
                zg[(size_t)t * OUT_DIM + n] = f2bf((accg[mi][ni][reg] + mb_) * sig);
            }
        }
}

// ---------------- G3: LayerNorm + residual (bf16 in, fp32 out) + final_state copy ------------
__global__ __launch_bounds__(256) void g3_ln(const unsigned short* __restrict__ zg,
        const unsigned short* __restrict__ sk2, const float* __restrict__ fstate,
        float* __restrict__ out, int out_size)
{
    __shared__ float sb[4], qb[4];
    __shared__ float mu_s, rstd_s;
    const int t = blockIdx.x;
    const int tid = threadIdx.x;
    ushort4 zu = *(const ushort4*)&zg [(size_t)t * OUT_DIM + tid * 4];
    ushort4 su = *(const ushort4*)&sk2[(size_t)t * OUT_DIM + tid * 4];
    float z0 = bf2f(zu.x), z1 = bf2f(zu.y), z2 = bf2f(zu.z), z3 = bf2f(zu.w);
    float s0 = bf2f(su.x), s1 = bf2f(su.y), s2 = bf2f(su.z), s3 = bf2f(su.w);
    float s = z0 + z1 + z2 + z3;
    float q = z0*z0 + z1*z1 + z2*z2 + z3*z3;
    #pragma unroll
    for (int off = 32; off > 0; off >>= 1) {
        s += __shfl_down(s, off, 64);
        q += __shfl_down(q, off, 64);
    }
    int wid = tid >> 6;
    if ((tid & 63) == 0) { sb[wid] = s; qb[wid] = q; }
    __syncthreads();
    if (tid == 0) {
        float S = sb[0] + sb[1] + sb[2] + sb[3];
        float Q = qb[0] + qb[1] + qb[2] + qb[3];
        float mu = S * (1.f / 1024.f);
        float var = Q * (1.f / 1024.f) - mu * mu;
        mu_s = mu; rstd_s = rsqrtf(var + 1e-5f);
    }
    __syncthreads();
    float mu = mu_s, rs = rstd_s;
    float4 o;
    o.x = (z0 - mu) * rs + s0;
    o.y = (z1 - mu) * rs + s1;
    o.z = (z2 - mu) * rs + s2;
    o.w = (z3 - mu) * rs + s3;
    *(float4*)&out[(size_t)t * OUT_DIM + tid * 4] = o;

    if (t < 8) {   // folded g4: final_state copy
        int i = t * 256 + tid;
        long long base = (long long)T_DIM * OUT_DIM;
        if (base + i < (long long)out_size) out[base + i] = fstate[i];
    }
}

extern "C" void kernel_launch(void* const* d_in, const int* in_sizes, int n_in,
                              void* d_out, int out_size, void* d_ws, size_t ws_size,
                              hipStream_t stream) {
    const float* x        = (const float*)d_in[0];
    const float* state_re = (const float*)d_in[1];
    const float* state_im = (const float*)d_in[2];
    const void*  startp   = d_in[3];
    const float* pre_w    = (const float*)d_in[5];
    const float* pre_b    = (const float*)d_in[6];
    const float* gi_w     = (const float*)d_in[7];
    const float* gi_b     = (const float*)d_in[8];
    const float* go_w     = (const float*)d_in[9];
    const float* go_b     = (const float*)d_in[10];
    const float* skip_w   = (const float*)d_in[11];
    const float* skip_b   = (const float*)d_in[12];
    const float* mix_w    = (const float*)d_in[13];
    const float* mix_b    = (const float*)d_in[14];
    const float* ffa_a    = (const float*)d_in[15];
    const float* ffa_b    = (const float*)d_in[16];

    float* ws = (float*)d_ws;
    float*          gxT    = ws;
    unsigned short* zinb   = (unsigned short*)(ws + 8912896);
    unsigned short* xb     = (unsigned short*)(ws + 17301504);
    unsigned short* gob    = (unsigned short*)(ws + 21495808);
    unsigned short* skb    = (unsigned short*)(ws + 22020096);
    unsigned short* mixb   = (unsigned short*)(ws + 22544384);
    unsigned short* zg     = (unsigned short*)(ws + 23592960);
    unsigned short* sk2    = (unsigned short*)(ws + 27787264);
    float*          fstate = ws + 31981568;
    unsigned char*  mask   = (unsigned char*)(ws + 31983616);
    unsigned long long* mask64 = (unsigned long long*)(ws + 31985664);
    unsigned short* pwb    = zg;            // borrow zg region pre-gA
    unsigned short* gwb    = zg + 65536;
    float* out = (float*)d_out;

    hipLaunchKernelGGL(c0_conv,  dim3(1536), dim3(256),  0, stream, x, go_w, skip_w, mix_w, pre_w, gi_w,
                                                          startp, xb, gob, skb, mixb, pwb, gwb, mask, mask64);
    hipLaunchKernelGGL(k1_mfma,  dim3(256),  dim3(256),  0, stream, xb, pwb, gwb, pre_b, gi_b, gxT);
    hipLaunchKernelGGL(k2_scan,  dim3(256),  dim3(1024), 0, stream, gxT, mask64, state_re, state_im, ffa_a, ffa_b, zinb, fstate);
    hipLaunchKernelGGL(gA_gemm,  dim3(256),  dim3(512),  0, stream, xb, zinb, gob, skb, mixb, go_b, skip_b, mix_b, zg, sk2);
    hipLaunchKernelGGL(g3_ln,    dim3(8192), dim3(256),  0, stream, zg, sk2, fstate, out, out_size);
}